// Round 1
// baseline (12346.453 us; speedup 1.0000x reference)
//
#include <hip/hip_runtime.h>
#include <math.h>

// ---------------------------------------------------------------------------
// MultiScaleRetriever fp32 pipeline (round 1: correctness-first, VALU GEMM)
// B=1024 q rows, N=100000 bank rows, D=1024, S=2 scales, top_m=32
// ---------------------------------------------------------------------------

static inline size_t align256(size_t x){ return (x + 255) & ~size_t(255); }

// ---------- per-row 1/max(||x||,1e-12) (one wave per row) ----------
__global__ __launch_bounds__(256) void row_rnorm_kernel(
    const float* __restrict__ X, float* __restrict__ rn, int rows, int D)
{
  int wv = threadIdx.x >> 6, lane = threadIdx.x & 63;
  int r = blockIdx.x * 4 + wv;
  if (r >= rows) return;
  const float4* xr = (const float4*)(X + (size_t)r * D);
  int nv = D >> 2;
  float ss = 0.f;
  for (int i = lane; i < nv; i += 64){
    float4 v = xr[i];
    ss = fmaf(v.x,v.x, fmaf(v.y,v.y, fmaf(v.z,v.z, fmaf(v.w,v.w, ss))));
  }
  #pragma unroll
  for (int off = 32; off; off >>= 1) ss += __shfl_xor(ss, off);
  if (lane == 0) rn[r] = 1.f / fmaxf(sqrtf(ss), 1e-12f);
}

// ---------- NT GEMM: C[m,n] = sum_k A[m,k]*B[n,k]*(bscale?bscale[n]:1) (+bias[n]) (+=C) ----------
// 256 threads. Tile: (RM*64) x (RN*64), BK=16. Thread micro-tile: RM x RN blocks of 4x4,
// split at 64-float stride so LDS float4 reads are 2-way-aliased (free on CDNA4).
template<int RM, int RN, bool ACCUM>
__global__ __launch_bounds__(256) void gemm_nt_kernel(
    const float* __restrict__ A, const float* __restrict__ B,
    const float* __restrict__ bias, const float* __restrict__ bscale,
    float* __restrict__ C, int M, int Nn, int K, int Brows, int ldc)
{
  __shared__ float As[16][RM*64 + 4];
  __shared__ float Bs[16][RN*64 + 4];
  const int t  = threadIdx.x;
  const int tm = t >> 4, tn = t & 15;
  const int m0 = blockIdx.y * (RM*64), n0 = blockIdx.x * (RN*64);

  float acc[RM][RN][4][4];
  #pragma unroll
  for (int r=0;r<RM;++r)
    #pragma unroll
    for (int c=0;c<RN;++c)
      #pragma unroll
      for (int i=0;i<4;++i)
        #pragma unroll
        for (int j=0;j<4;++j) acc[r][c][i][j]=0.f;

  for (int kp = 0; kp < K; kp += 16){
    #pragma unroll
    for (int l = 0; l < RM; ++l){
      int li = t + l*256;
      int row = li >> 2, kq = (li & 3) << 2;
      float4 v = *(const float4*)(A + (size_t)(m0+row)*K + kp + kq);
      As[kq+0][row]=v.x; As[kq+1][row]=v.y; As[kq+2][row]=v.z; As[kq+3][row]=v.w;
    }
    #pragma unroll
    for (int l = 0; l < RN; ++l){
      int li = t + l*256;
      int row = li >> 2, kq = (li & 3) << 2;
      int gn = n0 + row;
      float4 v = make_float4(0.f,0.f,0.f,0.f);
      float sc = 1.f;
      if (gn < Brows){
        v = *(const float4*)(B + (size_t)gn*K + kp + kq);
        if (bscale) sc = bscale[gn];
      }
      Bs[kq+0][row]=v.x*sc; Bs[kq+1][row]=v.y*sc; Bs[kq+2][row]=v.z*sc; Bs[kq+3][row]=v.w*sc;
    }
    __syncthreads();
    #pragma unroll
    for (int kk = 0; kk < 16; ++kk){
      float av[RM][4], bv[RN][4];
      #pragma unroll
      for (int r=0;r<RM;++r){
        float4 a = *(const float4*)&As[kk][r*64 + tm*4];
        av[r][0]=a.x; av[r][1]=a.y; av[r][2]=a.z; av[r][3]=a.w;
      }
      #pragma unroll
      for (int c=0;c<RN;++c){
        float4 b = *(const float4*)&Bs[kk][c*64 + tn*4];
        bv[c][0]=b.x; bv[c][1]=b.y; bv[c][2]=b.z; bv[c][3]=b.w;
      }
      #pragma unroll
      for (int r=0;r<RM;++r)
        #pragma unroll
        for (int c=0;c<RN;++c)
          #pragma unroll
          for (int i=0;i<4;++i)
            #pragma unroll
            for (int j=0;j<4;++j)
              acc[r][c][i][j] = fmaf(av[r][i], bv[c][j], acc[r][c][i][j]);
    }
    __syncthreads();
  }

  #pragma unroll
  for (int r=0;r<RM;++r){
    #pragma unroll
    for (int i=0;i<4;++i){
      int gm = m0 + r*64 + tm*4 + i;
      #pragma unroll
      for (int c=0;c<RN;++c){
        int gn = n0 + c*64 + tn*4;
        if (gn >= Nn) continue;
        float* cp = C + (size_t)gm*ldc + gn;
        float o0=acc[r][c][i][0], o1=acc[r][c][i][1], o2=acc[r][c][i][2], o3=acc[r][c][i][3];
        if (gn + 3 < Nn){
          float4 o = make_float4(o0,o1,o2,o3);
          if (bias){ float4 bb = *(const float4*)&bias[gn]; o.x+=bb.x; o.y+=bb.y; o.z+=bb.z; o.w+=bb.w; }
          if (ACCUM){ float4 cc = *(const float4*)cp; o.x+=cc.x; o.y+=cc.y; o.z+=cc.z; o.w+=cc.w; }
          *(float4*)cp = o;
        } else {
          float ov[4] = {o0,o1,o2,o3};
          for (int j=0;j<4;++j){
            if (gn + j < Nn){
              float o = ov[j];
              if (bias)  o += bias[gn+j];
              if (ACCUM) o += cp[j];
              cp[j] = o;
            }
          }
        }
      }
    }
  }
}

// ---------- per-(row,chunk) top-32 of chunk scores via LDS tournament ----------
// one block per row; strided per-thread registers (m,pos), shuffle argmax, owner rescans.
__global__ __launch_bounds__(256) void chunk_topk_kernel(
    const float* __restrict__ scores, int ncols, int ldc,
    float* __restrict__ cand_s, int* __restrict__ cand_i,
    int col0, int chunk, int nchunks, int topm)
{
  extern __shared__ float vals[];
  __shared__ float wv[4]; __shared__ int wp[4];
  __shared__ int winp_s;
  __shared__ float out_s[64]; __shared__ int out_i[64];
  const int row = blockIdx.x, t = threadIdx.x;
  const float* sr = scores + (size_t)row * ldc;

  int nc4 = ncols >> 2;
  const float4* sr4 = (const float4*)sr;
  for (int j = t; j < nc4; j += 256) ((float4*)vals)[j] = sr4[j];
  for (int j = (nc4<<2) + t; j < ncols; j += 256) vals[j] = sr[j];
  __syncthreads();

  float m = -INFINITY; int mp = 0x7fffffff;
  for (int j = t; j < ncols; j += 256){
    float v = vals[j];
    if (v > m){ m = v; mp = j; }
  }
  const int lane = t & 63, wid = t >> 6;

  for (int it = 0; it < topm; ++it){
    float rm = m; int rp = mp;
    #pragma unroll
    for (int off = 32; off; off >>= 1){
      float ov = __shfl_xor(rm, off); int op = __shfl_xor(rp, off);
      if (ov > rm || (ov == rm && op < rp)){ rm = ov; rp = op; }
    }
    if (lane == 0){ wv[wid] = rm; wp[wid] = rp; }
    __syncthreads();
    if (t == 0){
      float bv = wv[0]; int bp = wp[0];
      for (int w = 1; w < 4; ++w)
        if (wv[w] > bv || (wv[w] == bv && wp[w] < bp)){ bv = wv[w]; bp = wp[w]; }
      winp_s = bp;
      out_s[it] = bv; out_i[it] = col0 + bp;
    }
    __syncthreads();
    int wpos = winp_s;
    if ((wpos & 255) == t){
      vals[wpos] = -INFINITY;
      m = -INFINITY; mp = 0x7fffffff;
      for (int j = t; j < ncols; j += 256){
        float v = vals[j];
        if (v > m || (v == m && j < mp)){ m = v; mp = j; }
      }
    }
    __syncthreads();
  }
  if (t < topm){
    size_t o = ((size_t)row * nchunks + chunk) * topm + t;
    cand_s[o] = out_s[t];
    cand_i[o] = out_i[t];
  }
}

// ---------- final select (top-32 of all chunk candidates) + softmax + gather ----------
__global__ __launch_bounds__(256) void select_softmax_gather_kernel(
    const float* __restrict__ cand_s, const int* __restrict__ cand_i,
    const float* __restrict__ pnorm, const float* __restrict__ bank,
    float* __restrict__ z, int ncand, int D, int topm, float invtemp)
{
  __shared__ float vs[2048]; __shared__ int vi[2048];
  __shared__ float wv[4]; __shared__ int wk[4], wp[4];
  __shared__ int winp_s;
  __shared__ float sel_s[64]; __shared__ int sel_i[64];
  const int row = blockIdx.x, t = threadIdx.x;
  const float* cs = cand_s + (size_t)row * ncand;
  const int*  ci = cand_i + (size_t)row * ncand;
  for (int j = t; j < ncand; j += 256){ vs[j] = cs[j]; vi[j] = ci[j]; }
  __syncthreads();

  float m = -INFINITY; int mk = 0x7fffffff, mp = 0x7fffffff;
  for (int j = t; j < ncand; j += 256){
    float v = vs[j]; int k = vi[j];
    if (v > m || (v == m && k < mk)){ m = v; mk = k; mp = j; }
  }
  const int lane = t & 63, wid = t >> 6;

  for (int it = 0; it < topm; ++it){
    float rm = m; int rk = mk, rp = mp;
    #pragma unroll
    for (int off = 32; off; off >>= 1){
      float ov = __shfl_xor(rm, off); int ok = __shfl_xor(rk, off); int op = __shfl_xor(rp, off);
      if (ov > rm || (ov == rm && ok < rk)){ rm = ov; rk = ok; rp = op; }
    }
    if (lane == 0){ wv[wid] = rm; wk[wid] = rk; wp[wid] = rp; }
    __syncthreads();
    if (t == 0){
      float bv = wv[0]; int bk = wk[0], bp = wp[0];
      for (int w = 1; w < 4; ++w)
        if (wv[w] > bv || (wv[w] == bv && wk[w] < bk)){ bv = wv[w]; bk = wk[w]; bp = wp[w]; }
      winp_s = bp;
      sel_s[it] = bv; sel_i[it] = bk;
    }
    __syncthreads();
    if (winp_s == mp){
      vs[mp] = -INFINITY;
      m = -INFINITY; mk = 0x7fffffff; mp = 0x7fffffff;
      for (int j = t; j < ncand; j += 256){
        float v = vs[j]; int k = vi[j];
        if (v > m || (v == m && k < mk)){ m = v; mk = k; mp = j; }
      }
    }
    __syncthreads();
  }

  if (t == 0){
    float pn = pnorm[row] * invtemp;         // scores were raw p.khat; fold ||p||^-1 here
    float mx = sel_s[0] * pn;                // extraction order is descending -> sel_s[0] is max
    float sum = 0.f;
    for (int i = 0; i < topm; ++i){
      float w = expf(sel_s[i]*pn - mx);
      sel_s[i] = w; sum += w;
    }
    float inv = 1.f / sum;
    for (int i = 0; i < topm; ++i) sel_s[i] *= inv;
  }
  __syncthreads();

  for (int d4 = t; d4 < (D >> 2); d4 += 256){
    float ax=0.f, ay=0.f, az=0.f, aw=0.f;
    for (int i = 0; i < topm; ++i){
      float a = sel_s[i];
      const float4 v = *(const float4*)(bank + (size_t)sel_i[i]*D + (d4<<2));
      ax = fmaf(a, v.x, ax); ay = fmaf(a, v.y, ay);
      az = fmaf(a, v.z, az); aw = fmaf(a, v.w, aw);
    }
    *(float4*)(z + (size_t)row*D + (d4<<2)) = make_float4(ax,ay,az,aw);
  }
}

// ---------- LayerNorm ----------
__global__ __launch_bounds__(256) void layernorm_kernel(
    const float* __restrict__ ref, const float* __restrict__ gamma,
    const float* __restrict__ beta, float* __restrict__ out, int D, float eps)
{
  __shared__ float s1[4], s2[4];
  const int row = blockIdx.x, t = threadIdx.x;
  const float4* xr = (const float4*)(ref + (size_t)row*D);
  int nv = D >> 2;
  float sum = 0.f, ssq = 0.f;
  for (int i = t; i < nv; i += 256){
    float4 v = xr[i];
    sum += v.x+v.y+v.z+v.w;
    ssq = fmaf(v.x,v.x, fmaf(v.y,v.y, fmaf(v.z,v.z, fmaf(v.w,v.w, ssq))));
  }
  const int lane = t & 63, wid = t >> 6;
  #pragma unroll
  for (int off = 32; off; off >>= 1){ sum += __shfl_xor(sum, off); ssq += __shfl_xor(ssq, off); }
  if (lane == 0){ s1[wid] = sum; s2[wid] = ssq; }
  __syncthreads();
  sum = s1[0]+s1[1]+s1[2]+s1[3];
  ssq = s2[0]+s2[1]+s2[2]+s2[3];
  float mu  = sum / (float)D;
  float var = ssq / (float)D - mu*mu;
  float rs  = rsqrtf(var + eps);
  const float4* g4 = (const float4*)gamma;
  const float4* b4 = (const float4*)beta;
  float4* o4 = (float4*)(out + (size_t)row*D);
  for (int i = t; i < nv; i += 256){
    float4 v = xr[i], g = g4[i], bb = b4[i];
    float4 o;
    o.x = (v.x-mu)*rs*g.x + bb.x;
    o.y = (v.y-mu)*rs*g.y + bb.y;
    o.z = (v.z-mu)*rs*g.z + bb.z;
    o.w = (v.w-mu)*rs*g.w + bb.w;
    o4[i] = o;
  }
}

// ---------------------------------------------------------------------------
extern "C" void kernel_launch(void* const* d_in, const int* in_sizes, int n_in,
                              void* d_out, int out_size, void* d_ws, size_t ws_size,
                              hipStream_t stream)
{
  const float* q       = (const float*)d_in[0];
  const float* bank    = (const float*)d_in[1];
  const float* proj_w  = (const float*)d_in[2];
  const float* proj_b  = (const float*)d_in[3];
  const float* unify_w = (const float*)d_in[4];
  const float* unify_b = (const float*)d_in[5];
  const float* gamma   = (const float*)d_in[6];
  const float* beta    = (const float*)d_in[7];

  const int D = in_sizes[6];
  const int B = in_sizes[0] / D;
  const int N = in_sizes[1] / D;
  const int S = in_sizes[2] / (D * D);
  const int TOPM = 32;              // setup_inputs fixed value
  const float INVTEMP = 1.0f / 0.07f;

  // --- workspace sizing: pick scores-chunk width that fits ws ---
  size_t fixed = align256((size_t)N*4) + align256((size_t)B*4) + 3*align256((size_t)B*D*4);
  const int ncopts[4] = {12544, 6272, 3136, 1568};
  int NC = 1568;
  for (int ci = 0; ci < 4; ++ci){
    int cand = ncopts[ci];
    int nch = (N + cand - 1) / cand;
    size_t tot = fixed + align256((size_t)B*cand*4) + 2*align256((size_t)B*nch*TOPM*4);
    if (tot <= ws_size){ NC = cand; break; }
  }
  const int NCH = (N + NC - 1) / NC;

  char* wsb = (char*)d_ws;
  size_t off = 0;
  auto take = [&](size_t bytes)->char*{ char* p = wsb + off; off += align256(bytes); return p; };
  float* rn_bank = (float*)take((size_t)N*4);
  float* pnorm   = (float*)take((size_t)B*4);
  float* p       = (float*)take((size_t)B*D*4);
  float* z       = (float*)take((size_t)B*D*4);
  float* ref     = (float*)take((size_t)B*D*4);
  float* scores  = (float*)take((size_t)B*NC*4);
  float* cand_s  = (float*)take((size_t)B*NCH*TOPM*4);
  int*   cand_i  = (int*)  take((size_t)B*NCH*TOPM*4);

  // 1) bank key inverse norms
  row_rnorm_kernel<<<(N+3)/4, 256, 0, stream>>>(bank, rn_bank, N, D);

  for (int s = 0; s < S; ++s){
    // 2) p = q @ proj_w[s]^T + proj_b[s]
    dim3 g1(D/64, B/64);
    gemm_nt_kernel<1,1,false><<<g1, 256, 0, stream>>>(
        q, proj_w + (size_t)s*D*D, proj_b + (size_t)s*D, nullptr,
        p, B, D, D, D, D);
    // 3) ||p|| row norms (fold into softmax later; top-k order invariant to +scale)
    row_rnorm_kernel<<<(B+3)/4, 256, 0, stream>>>(p, pnorm, B, D);

    // 4) chunked scores + per-chunk top-32
    for (int c = 0; c < NCH; ++c){
      int n0 = c * NC;
      int nv = N - n0; if (nv > NC) nv = NC;
      dim3 g2((nv + 127)/128, B/128);
      gemm_nt_kernel<2,2,false><<<g2, 256, 0, stream>>>(
          p, bank + (size_t)n0*D, nullptr, rn_bank + n0,
          scores, B, nv, D, nv, NC);
      chunk_topk_kernel<<<B, 256, (size_t)NC*4, stream>>>(
          scores, nv, NC, cand_s, cand_i, n0, c, NCH, TOPM);
    }

    // 5) merge candidates, softmax(T=0.07), weighted gather into z
    select_softmax_gather_kernel<<<B, 256, 0, stream>>>(
        cand_s, cand_i, pnorm, bank, z, NCH*TOPM, D, TOPM, INVTEMP);

    // 6) ref (+)= z @ unify_w[s]^T + unify_b[s]
    if (s == 0)
      gemm_nt_kernel<1,1,false><<<g1, 256, 0, stream>>>(
          z, unify_w + (size_t)s*D*D, unify_b + (size_t)s*D, nullptr,
          ref, B, D, D, D, D);
    else
      gemm_nt_kernel<1,1,true><<<g1, 256, 0, stream>>>(
          z, unify_w + (size_t)s*D*D, unify_b + (size_t)s*D, nullptr,
          ref, B, D, D, D, D);
  }

  // 7) LayerNorm -> out
  layernorm_kernel<<<B, 256, 0, stream>>>(ref, gamma, beta, (float*)d_out, D, 1e-5f);
}

// Round 4
// 9350.115 us; speedup vs baseline: 1.3205x; 1.3205x over previous
//
#include <hip/hip_runtime.h>
#include <math.h>

// ---------------------------------------------------------------------------
// MultiScaleRetriever round 4: R3 pipeline + fp32 RESCORE of all candidates.
// bf16x3 MFMA generates candidates only; final top-32/softmax uses exact fp32
// scores (fixes the deterministic top-32/33 flip that failed R2/R3).
// ---------------------------------------------------------------------------

static inline size_t align256(size_t x){ return (x + 255) & ~size_t(255); }

typedef short bf16x8 __attribute__((ext_vector_type(8)));
typedef float f32x4  __attribute__((ext_vector_type(4)));

// fp32 -> bf16 round-to-nearest-even
__device__ inline unsigned short f2bf(float f){
  unsigned int u = __float_as_uint(f);
  u += 0x7fffu + ((u >> 16) & 1u);
  return (unsigned short)(u >> 16);
}
__device__ inline float bf2f(unsigned short h){
  return __uint_as_float(((unsigned int)h) << 16);
}
__device__ inline void pack_hilo(float4 v, uint2& hw, uint2& lw){
  unsigned short h0=f2bf(v.x), h1=f2bf(v.y), h2=f2bf(v.z), h3=f2bf(v.w);
  unsigned short g0=f2bf(v.x-bf2f(h0)), g1=f2bf(v.y-bf2f(h1)),
                 g2=f2bf(v.z-bf2f(h2)), g3=f2bf(v.w-bf2f(h3));
  hw.x = (unsigned)h0 | ((unsigned)h1<<16); hw.y = (unsigned)h2 | ((unsigned)h3<<16);
  lw.x = (unsigned)g0 | ((unsigned)g1<<16); lw.y = (unsigned)g2 | ((unsigned)g3<<16);
}

// ---------- per-row 1/max(||x||,1e-12) (one wave per row) ----------
__global__ __launch_bounds__(256) void row_rnorm_kernel(
    const float* __restrict__ X, float* __restrict__ rn, int rows, int D)
{
  int wv = threadIdx.x >> 6, lane = threadIdx.x & 63;
  int r = blockIdx.x * 4 + wv;
  if (r >= rows) return;
  const float4* xr = (const float4*)(X + (size_t)r * D);
  int nv = D >> 2;
  float ss = 0.f;
  for (int i = lane; i < nv; i += 64){
    float4 v = xr[i];
    ss = fmaf(v.x,v.x, fmaf(v.y,v.y, fmaf(v.z,v.z, fmaf(v.w,v.w, ss))));
  }
  #pragma unroll
  for (int off = 32; off; off >>= 1) ss += __shfl_xor(ss, off);
  if (lane == 0) rn[r] = 1.f / fmaxf(sqrtf(ss), 1e-12f);
}

// ---------- fp32 NT GEMM (proj/unify): C[m,n]=sum_k A[m,k]B[n,k] ----------
template<int RM, int RN, bool ACCUM>
__global__ __launch_bounds__(256) void gemm_nt_kernel(
    const float* __restrict__ A, const float* __restrict__ B,
    const float* __restrict__ bias, const float* __restrict__ bscale,
    float* __restrict__ C, int M, int Nn, int K, int Brows, int ldc)
{
  __shared__ float As[16][RM*64 + 4];
  __shared__ float Bs[16][RN*64 + 4];
  const int t  = threadIdx.x;
  const int tm = t >> 4, tn = t & 15;
  const int m0 = blockIdx.y * (RM*64), n0 = blockIdx.x * (RN*64);

  float acc[RM][RN][4][4];
  #pragma unroll
  for (int r=0;r<RM;++r)
    #pragma unroll
    for (int c=0;c<RN;++c)
      #pragma unroll
      for (int i=0;i<4;++i)
        #pragma unroll
        for (int j=0;j<4;++j) acc[r][c][i][j]=0.f;

  for (int kp = 0; kp < K; kp += 16){
    #pragma unroll
    for (int l = 0; l < RM; ++l){
      int li = t + l*256;
      int row = li >> 2, kq = (li & 3) << 2;
      float4 v = *(const float4*)(A + (size_t)(m0+row)*K + kp + kq);
      As[kq+0][row]=v.x; As[kq+1][row]=v.y; As[kq+2][row]=v.z; As[kq+3][row]=v.w;
    }
    #pragma unroll
    for (int l = 0; l < RN; ++l){
      int li = t + l*256;
      int row = li >> 2, kq = (li & 3) << 2;
      int gn = n0 + row;
      float4 v = make_float4(0.f,0.f,0.f,0.f);
      float sc = 1.f;
      if (gn < Brows){
        v = *(const float4*)(B + (size_t)gn*K + kp + kq);
        if (bscale) sc = bscale[gn];
      }
      Bs[kq+0][row]=v.x*sc; Bs[kq+1][row]=v.y*sc; Bs[kq+2][row]=v.z*sc; Bs[kq+3][row]=v.w*sc;
    }
    __syncthreads();
    #pragma unroll
    for (int kk = 0; kk < 16; ++kk){
      float av[RM][4], bv[RN][4];
      #pragma unroll
      for (int r=0;r<RM;++r){
        float4 a = *(const float4*)&As[kk][r*64 + tm*4];
        av[r][0]=a.x; av[r][1]=a.y; av[r][2]=a.z; av[r][3]=a.w;
      }
      #pragma unroll
      for (int c=0;c<RN;++c){
        float4 b = *(const float4*)&Bs[kk][c*64 + tn*4];
        bv[c][0]=b.x; bv[c][1]=b.y; bv[c][2]=b.z; bv[c][3]=b.w;
      }
      #pragma unroll
      for (int r=0;r<RM;++r)
        #pragma unroll
        for (int c=0;c<RN;++c)
          #pragma unroll
          for (int i=0;i<4;++i)
            #pragma unroll
            for (int j=0;j<4;++j)
              acc[r][c][i][j] = fmaf(av[r][i], bv[c][j], acc[r][c][i][j]);
    }
    __syncthreads();
  }

  #pragma unroll
  for (int r=0;r<RM;++r){
    #pragma unroll
    for (int i=0;i<4;++i){
      int gm = m0 + r*64 + tm*4 + i;
      #pragma unroll
      for (int c=0;c<RN;++c){
        int gn = n0 + c*64 + tn*4;
        if (gn >= Nn) continue;
        float* cp = C + (size_t)gm*ldc + gn;
        float o0=acc[r][c][i][0], o1=acc[r][c][i][1], o2=acc[r][c][i][2], o3=acc[r][c][i][3];
        if (gn + 3 < Nn){
          float4 o = make_float4(o0,o1,o2,o3);
          if (bias){ float4 bb = *(const float4*)&bias[gn]; o.x+=bb.x; o.y+=bb.y; o.z+=bb.z; o.w+=bb.w; }
          if (ACCUM){ float4 cc = *(const float4*)cp; o.x+=cc.x; o.y+=cc.y; o.z+=cc.z; o.w+=cc.w; }
          *(float4*)cp = o;
        } else {
          float ov[4] = {o0,o1,o2,o3};
          for (int j=0;j<4;++j){
            if (gn + j < Nn){
              float o = ov[j];
              if (bias)  o += bias[gn+j];
              if (ACCUM) o += cp[j];
              cp[j] = o;
            }
          }
        }
      }
    }
  }
}

// ---------- scores GEMM: bf16x3 split MFMA (candidate generation only) ----------
__global__ __launch_bounds__(256) void scores_mfma_kernel(
    const float* __restrict__ A, const float* __restrict__ Bm,
    const float* __restrict__ rn, float* __restrict__ C,
    int M, int Nn, int K, int ldc)
{
  __shared__ unsigned short Ah_s[128][40];
  __shared__ unsigned short Al_s[128][40];
  __shared__ unsigned short Bh_s[128][40];
  __shared__ unsigned short Bl_s[128][40];

  const int t = threadIdx.x;
  const int lane = t & 63, wid = t >> 6;
  const int wm = wid >> 1, wn = wid & 1;
  const int l15 = lane & 15, l4 = lane >> 4;
  const int m0 = blockIdx.y * 128, n0 = blockIdx.x * 128;

  f32x4 acc[4][4];
  #pragma unroll
  for (int i=0;i<4;++i)
    #pragma unroll
    for (int j=0;j<4;++j) acc[i][j] = (f32x4)0.f;

  for (int kp = 0; kp < K; kp += 32){
    #pragma unroll
    for (int i = 0; i < 4; ++i){
      int li  = t + i*256;
      int row = li >> 3;
      int kq  = (li & 7) << 2;
      float4 va = *(const float4*)(A + (size_t)(m0+row)*K + kp + kq);
      uint2 hw, lw; pack_hilo(va, hw, lw);
      *(uint2*)&Ah_s[row][kq] = hw;
      *(uint2*)&Al_s[row][kq] = lw;

      int gn = n0 + row;
      float4 vb = make_float4(0.f,0.f,0.f,0.f);
      float sc = 0.f;
      if (gn < Nn){ vb = *(const float4*)(Bm + (size_t)gn*K + kp + kq); sc = rn[gn]; }
      vb.x*=sc; vb.y*=sc; vb.z*=sc; vb.w*=sc;
      pack_hilo(vb, hw, lw);
      *(uint2*)&Bh_s[row][kq] = hw;
      *(uint2*)&Bl_s[row][kq] = lw;
    }
    __syncthreads();

    bf16x8 bh[4], bl[4];
    #pragma unroll
    for (int fn = 0; fn < 4; ++fn){
      int bcol = wn*64 + fn*16 + l15;
      bh[fn] = *(const bf16x8*)&Bh_s[bcol][l4*8];
      bl[fn] = *(const bf16x8*)&Bl_s[bcol][l4*8];
    }
    #pragma unroll
    for (int fm = 0; fm < 4; ++fm){
      int arow = wm*64 + fm*16 + l15;
      bf16x8 ah = *(const bf16x8*)&Ah_s[arow][l4*8];
      bf16x8 al = *(const bf16x8*)&Al_s[arow][l4*8];
      #pragma unroll
      for (int fn = 0; fn < 4; ++fn){
        acc[fm][fn] = __builtin_amdgcn_mfma_f32_16x16x32_bf16(ah, bh[fn], acc[fm][fn], 0,0,0);
        acc[fm][fn] = __builtin_amdgcn_mfma_f32_16x16x32_bf16(ah, bl[fn], acc[fm][fn], 0,0,0);
        acc[fm][fn] = __builtin_amdgcn_mfma_f32_16x16x32_bf16(al, bh[fn], acc[fm][fn], 0,0,0);
      }
    }
    __syncthreads();
  }

  #pragma unroll
  for (int fm = 0; fm < 4; ++fm){
    int row = m0 + wm*64 + fm*16 + l4*4;
    #pragma unroll
    for (int fn = 0; fn < 4; ++fn){
      int col = n0 + wn*64 + fn*16 + l15;
      if (col < Nn){
        float* cp = C + (size_t)row*ldc + col;
        #pragma unroll
        for (int r = 0; r < 4; ++r) cp[(size_t)r*ldc] = acc[fm][fn][r];
      }
    }
  }
}

// ---------- per-(row,chunk) top-32 of chunk scores via LDS tournament ----------
__global__ __launch_bounds__(256) void chunk_topk_kernel(
    const float* __restrict__ scores, int ncols, int ldc,
    float* __restrict__ cand_s, int* __restrict__ cand_i,
    int col0, int chunk, int nchunks, int topm)
{
  extern __shared__ float vals[];
  __shared__ float wv[4]; __shared__ int wp[4];
  __shared__ int winp_s;
  __shared__ float out_s[64]; __shared__ int out_i[64];
  const int row = blockIdx.x, t = threadIdx.x;
  const float* sr = scores + (size_t)row * ldc;

  int nc4 = ncols >> 2;
  const float4* sr4 = (const float4*)sr;
  for (int j = t; j < nc4; j += 256) ((float4*)vals)[j] = sr4[j];
  for (int j = (nc4<<2) + t; j < ncols; j += 256) vals[j] = sr[j];
  __syncthreads();

  float m = -INFINITY; int mp = 0x7fffffff;
  for (int j = t; j < ncols; j += 256){
    float v = vals[j];
    if (v > m){ m = v; mp = j; }
  }
  const int lane = t & 63, wid = t >> 6;

  for (int it = 0; it < topm; ++it){
    float rm = m; int rp = mp;
    #pragma unroll
    for (int off = 32; off; off >>= 1){
      float ov = __shfl_xor(rm, off); int op = __shfl_xor(rp, off);
      if (ov > rm || (ov == rm && op < rp)){ rm = ov; rp = op; }
    }
    if (lane == 0){ wv[wid] = rm; wp[wid] = rp; }
    __syncthreads();
    if (t == 0){
      float bv = wv[0]; int bp = wp[0];
      for (int w = 1; w < 4; ++w)
        if (wv[w] > bv || (wv[w] == bv && wp[w] < bp)){ bv = wv[w]; bp = wp[w]; }
      winp_s = bp;
      out_s[it] = bv; out_i[it] = col0 + bp;
    }
    __syncthreads();
    int wpos = winp_s;
    if ((wpos & 255) == t){
      vals[wpos] = -INFINITY;
      m = -INFINITY; mp = 0x7fffffff;
      for (int j = t; j < ncols; j += 256){
        float v = vals[j];
        if (v > m || (v == m && j < mp)){ m = v; mp = j; }
      }
    }
    __syncthreads();
  }
  if (t < topm){
    size_t o = ((size_t)row * nchunks + chunk) * topm + t;
    cand_s[o] = out_s[t];
    cand_i[o] = out_i[t];
  }
}

// ---------- fp32 rescore + final top-32 + softmax + weighted gather ----------
// Candidates from bf16x3 chunks are rescored EXACTLY (fp32 dot of p row with
// each candidate bank row * rn), then top-32 selected on exact scores.
__global__ __launch_bounds__(256) void select_softmax_gather_kernel(
    const int* __restrict__ cand_i, const float* __restrict__ p,
    const float* __restrict__ rn_bank, const float* __restrict__ pnorm,
    const float* __restrict__ bank, float* __restrict__ z,
    int ncand, int D, int topm, float invtemp)
{
  __shared__ float p_s[1024];              // D = 1024 for this problem
  __shared__ float vs[2048]; __shared__ int vi[2048];
  __shared__ float wv[4]; __shared__ int wk[4], wp[4];
  __shared__ int winp_s;
  __shared__ float sel_s[64]; __shared__ int sel_i[64];
  const int row = blockIdx.x, t = threadIdx.x;
  const int lane = t & 63, wid = t >> 6;

  // load p row + candidate indices
  const float4* pr = (const float4*)(p + (size_t)row * D);
  for (int i = t; i < (D >> 2); i += 256) ((float4*)p_s)[i] = pr[i];
  const int* ci = cand_i + (size_t)row * ncand;
  for (int j = t; j < ncand; j += 256) vi[j] = ci[j];
  __syncthreads();

  // fp32 rescore: one wave per candidate (coalesced 16B/lane reads)
  const int nj = D >> 8;                   // float4 chunks of 64 lanes
  for (int c = wid; c < ncand; c += 4){
    int idx = vi[c];
    const float4* kr = (const float4*)(bank + (size_t)idx * D);
    float ss = 0.f;
    for (int j = 0; j < nj; ++j){
      float4 kv = kr[lane + j*64];
      float4 pv = *(const float4*)&p_s[(lane + j*64) << 2];
      ss = fmaf(pv.x,kv.x, fmaf(pv.y,kv.y, fmaf(pv.z,kv.z, fmaf(pv.w,kv.w, ss))));
    }
    #pragma unroll
    for (int off = 32; off; off >>= 1) ss += __shfl_xor(ss, off);
    if (lane == 0) vs[c] = ss * rn_bank[idx];
  }
  __syncthreads();

  // top-32 tournament on exact scores (tie-break on smaller bank index)
  float m = -INFINITY; int mk = 0x7fffffff, mp = 0x7fffffff;
  for (int j = t; j < ncand; j += 256){
    float v = vs[j]; int k = vi[j];
    if (v > m || (v == m && k < mk)){ m = v; mk = k; mp = j; }
  }

  for (int it = 0; it < topm; ++it){
    float rm = m; int rk = mk, rp = mp;
    #pragma unroll
    for (int off = 32; off; off >>= 1){
      float ov = __shfl_xor(rm, off); int ok = __shfl_xor(rk, off); int op = __shfl_xor(rp, off);
      if (ov > rm || (ov == rm && ok < rk)){ rm = ov; rk = ok; rp = op; }
    }
    if (lane == 0){ wv[wid] = rm; wk[wid] = rk; wp[wid] = rp; }
    __syncthreads();
    if (t == 0){
      float bv = wv[0]; int bk = wk[0], bp = wp[0];
      for (int w = 1; w < 4; ++w)
        if (wv[w] > bv || (wv[w] == bv && wk[w] < bk)){ bv = wv[w]; bk = wk[w]; bp = wp[w]; }
      winp_s = bp;
      sel_s[it] = bv; sel_i[it] = bk;
    }
    __syncthreads();
    if (winp_s == mp){
      vs[mp] = -INFINITY;
      m = -INFINITY; mk = 0x7fffffff; mp = 0x7fffffff;
      for (int j = t; j < ncand; j += 256){
        float v = vs[j]; int k = vi[j];
        if (v > m || (v == m && k < mk)){ m = v; mk = k; mp = j; }
      }
    }
    __syncthreads();
  }

  if (t == 0){
    float pn = pnorm[row] * invtemp;
    float mx = sel_s[0] * pn;
    float sum = 0.f;
    for (int i = 0; i < topm; ++i){
      float w = expf(sel_s[i]*pn - mx);
      sel_s[i] = w; sum += w;
    }
    float inv = 1.f / sum;
    for (int i = 0; i < topm; ++i) sel_s[i] *= inv;
  }
  __syncthreads();

  for (int d4 = t; d4 < (D >> 2); d4 += 256){
    float ax=0.f, ay=0.f, az=0.f, aw=0.f;
    for (int i = 0; i < topm; ++i){
      float a = sel_s[i];
      const float4 v = *(const float4*)(bank + (size_t)sel_i[i]*D + (d4<<2));
      ax = fmaf(a, v.x, ax); ay = fmaf(a, v.y, ay);
      az = fmaf(a, v.z, az); aw = fmaf(a, v.w, aw);
    }
    *(float4*)(z + (size_t)row*D + (d4<<2)) = make_float4(ax,ay,az,aw);
  }
}

// ---------- LayerNorm ----------
__global__ __launch_bounds__(256) void layernorm_kernel(
    const float* __restrict__ ref, const float* __restrict__ gamma,
    const float* __restrict__ beta, float* __restrict__ out, int D, float eps)
{
  __shared__ float s1[4], s2[4];
  const int row = blockIdx.x, t = threadIdx.x;
  const float4* xr = (const float4*)(ref + (size_t)row*D);
  int nv = D >> 2;
  float sum = 0.f, ssq = 0.f;
  for (int i = t; i < nv; i += 256){
    float4 v = xr[i];
    sum += v.x+v.y+v.z+v.w;
    ssq = fmaf(v.x,v.x, fmaf(v.y,v.y, fmaf(v.z,v.z, fmaf(v.w,v.w, ssq))));
  }
  const int lane = t & 63, wid = t >> 6;
  #pragma unroll
  for (int off = 32; off; off >>= 1){ sum += __shfl_xor(sum, off); ssq += __shfl_xor(ssq, off); }
  if (lane == 0){ s1[wid] = sum; s2[wid] = ssq; }
  __syncthreads();
  sum = s1[0]+s1[1]+s1[2]+s1[3];
  ssq = s2[0]+s2[1]+s2[2]+s2[3];
  float mu  = sum / (float)D;
  float var = ssq / (float)D - mu*mu;
  float rs  = rsqrtf(var + eps);
  const float4* g4 = (const float4*)gamma;
  const float4* b4 = (const float4*)beta;
  float4* o4 = (float4*)(out + (size_t)row*D);
  for (int i = t; i < nv; i += 256){
    float4 v = xr[i], g = g4[i], bb = b4[i];
    float4 o;
    o.x = (v.x-mu)*rs*g.x + bb.x;
    o.y = (v.y-mu)*rs*g.y + bb.y;
    o.z = (v.z-mu)*rs*g.z + bb.z;
    o.w = (v.w-mu)*rs*g.w + bb.w;
    o4[i] = o;
  }
}

// ---------------------------------------------------------------------------
extern "C" void kernel_launch(void* const* d_in, const int* in_sizes, int n_in,
                              void* d_out, int out_size, void* d_ws, size_t ws_size,
                              hipStream_t stream)
{
  const float* q       = (const float*)d_in[0];
  const float* bank    = (const float*)d_in[1];
  const float* proj_w  = (const float*)d_in[2];
  const float* proj_b  = (const float*)d_in[3];
  const float* unify_w = (const float*)d_in[4];
  const float* unify_b = (const float*)d_in[5];
  const float* gamma   = (const float*)d_in[6];
  const float* beta    = (const float*)d_in[7];

  const int D = in_sizes[6];
  const int B = in_sizes[0] / D;
  const int N = in_sizes[1] / D;
  const int S = in_sizes[2] / (D * D);
  const int TOPM = 32;
  const float INVTEMP = 1.0f / 0.07f;

  // --- workspace sizing: identical to round 1 (proven) ---
  size_t fixed = align256((size_t)N*4) + align256((size_t)B*4) + 3*align256((size_t)B*D*4);
  const int ncopts[4] = {12544, 6272, 3136, 1568};
  int NC = 1568;
  for (int ci = 0; ci < 4; ++ci){
    int cand = ncopts[ci];
    int nch = (N + cand - 1) / cand;
    size_t tot = fixed + align256((size_t)B*cand*4) + 2*align256((size_t)B*nch*TOPM*4);
    if (tot <= ws_size){ NC = cand; break; }
  }
  const int NCH = (N + NC - 1) / NC;

  char* wsb = (char*)d_ws;
  size_t off = 0;
  auto take = [&](size_t bytes)->char*{ char* p = wsb + off; off += align256(bytes); return p; };
  float* rn_bank = (float*)take((size_t)N*4);
  float* pnorm   = (float*)take((size_t)B*4);
  float* p       = (float*)take((size_t)B*D*4);
  float* z       = (float*)take((size_t)B*D*4);
  float* ref     = (float*)take((size_t)B*D*4);
  float* scores  = (float*)take((size_t)B*NC*4);
  float* cand_s  = (float*)take((size_t)B*NCH*TOPM*4);
  int*   cand_i  = (int*)  take((size_t)B*NCH*TOPM*4);

  // 1) bank key inverse norms
  row_rnorm_kernel<<<(N+3)/4, 256, 0, stream>>>(bank, rn_bank, N, D);

  for (int s = 0; s < S; ++s){
    // 2) p = q @ proj_w[s]^T + proj_b[s]
    dim3 g1(D/64, B/64);
    gemm_nt_kernel<1,1,false><<<g1, 256, 0, stream>>>(
        q, proj_w + (size_t)s*D*D, proj_b + (size_t)s*D, nullptr,
        p, B, D, D, D, D);
    // 3) ||p|| row norms (folded into softmax; top-k order invariant to +scale)
    row_rnorm_kernel<<<(B+3)/4, 256, 0, stream>>>(p, pnorm, B, D);

    // 4) chunked scores (bf16x3 MFMA, candidate generation) + per-chunk top-32
    for (int c = 0; c < NCH; ++c){
      int n0 = c * NC;
      int nv = N - n0; if (nv > NC) nv = NC;
      dim3 g2((nv + 127)/128, B/128);
      scores_mfma_kernel<<<g2, 256, 0, stream>>>(
          p, bank + (size_t)n0*D, rn_bank + n0,
          scores, B, nv, D, NC);
      chunk_topk_kernel<<<B, 256, (size_t)NC*4, stream>>>(
          scores, nv, NC, cand_s, cand_i, n0, c, NCH, TOPM);
    }

    // 5) fp32 rescore candidates + exact top-32 + softmax + gather into z
    select_softmax_gather_kernel<<<B, 256, 0, stream>>>(
        cand_i, p, rn_bank, pnorm, bank, z, NCH*TOPM, D, TOPM, INVTEMP);

    // 6) ref (+)= z @ unify_w[s]^T + unify_b[s]
    if (s == 0)
      gemm_nt_kernel<1,1,false><<<g1, 256, 0, stream>>>(
          z, unify_w + (size_t)s*D*D, unify_b + (size_t)s*D, nullptr,
          ref, B, D, D, D, D);
    else
      gemm_nt_kernel<1,1,true><<<g1, 256, 0, stream>>>(
          z, unify_w + (size_t)s*D*D, unify_b + (size_t)s*D, nullptr,
          ref, B, D, D, D, D);
  }

  // 7) LayerNorm -> out
  layernorm_kernel<<<B, 256, 0, stream>>>(ref, gamma, beta, (float*)d_out, D, 1e-5f);
}

// Round 6
// 4220.607 us; speedup vs baseline: 2.9253x; 2.2153x over previous
//
#include <hip/hip_runtime.h>
#include <math.h>

// ---------------------------------------------------------------------------
// MultiScaleRetriever round 5 (resubmit; container died before benching):
// replace serial top-32 tournament with threshold-filter selection
// (tau = 32nd of per-thread maxima, guaranteed superset), bitonic sorts,
// fp32 rescore of ~40 candidates.
// scores_mfma / proj / unify / LN unchanged from passing round 4.
// ---------------------------------------------------------------------------

static inline size_t align256(size_t x){ return (x + 255) & ~size_t(255); }

typedef short bf16x8 __attribute__((ext_vector_type(8)));
typedef float f32x4  __attribute__((ext_vector_type(4)));

__device__ inline unsigned short f2bf(float f){
  unsigned int u = __float_as_uint(f);
  u += 0x7fffu + ((u >> 16) & 1u);
  return (unsigned short)(u >> 16);
}
__device__ inline float bf2f(unsigned short h){
  return __uint_as_float(((unsigned int)h) << 16);
}
__device__ inline void pack_hilo(float4 v, uint2& hw, uint2& lw){
  unsigned short h0=f2bf(v.x), h1=f2bf(v.y), h2=f2bf(v.z), h3=f2bf(v.w);
  unsigned short g0=f2bf(v.x-bf2f(h0)), g1=f2bf(v.y-bf2f(h1)),
                 g2=f2bf(v.z-bf2f(h2)), g3=f2bf(v.w-bf2f(h3));
  hw.x = (unsigned)h0 | ((unsigned)h1<<16); hw.y = (unsigned)h2 | ((unsigned)h3<<16);
  lw.x = (unsigned)g0 | ((unsigned)g1<<16); lw.y = (unsigned)g2 | ((unsigned)g3<<16);
}

// ---------- per-row 1/max(||x||,1e-12) ----------
__global__ __launch_bounds__(256) void row_rnorm_kernel(
    const float* __restrict__ X, float* __restrict__ rn, int rows, int D)
{
  int wv = threadIdx.x >> 6, lane = threadIdx.x & 63;
  int r = blockIdx.x * 4 + wv;
  if (r >= rows) return;
  const float4* xr = (const float4*)(X + (size_t)r * D);
  int nv = D >> 2;
  float ss = 0.f;
  for (int i = lane; i < nv; i += 64){
    float4 v = xr[i];
    ss = fmaf(v.x,v.x, fmaf(v.y,v.y, fmaf(v.z,v.z, fmaf(v.w,v.w, ss))));
  }
  #pragma unroll
  for (int off = 32; off; off >>= 1) ss += __shfl_xor(ss, off);
  if (lane == 0) rn[r] = 1.f / fmaxf(sqrtf(ss), 1e-12f);
}

// ---------- fp32 NT GEMM (proj/unify) ----------
template<int RM, int RN, bool ACCUM>
__global__ __launch_bounds__(256) void gemm_nt_kernel(
    const float* __restrict__ A, const float* __restrict__ B,
    const float* __restrict__ bias, const float* __restrict__ bscale,
    float* __restrict__ C, int M, int Nn, int K, int Brows, int ldc)
{
  __shared__ float As[16][RM*64 + 4];
  __shared__ float Bs[16][RN*64 + 4];
  const int t  = threadIdx.x;
  const int tm = t >> 4, tn = t & 15;
  const int m0 = blockIdx.y * (RM*64), n0 = blockIdx.x * (RN*64);

  float acc[RM][RN][4][4];
  #pragma unroll
  for (int r=0;r<RM;++r)
    #pragma unroll
    for (int c=0;c<RN;++c)
      #pragma unroll
      for (int i=0;i<4;++i)
        #pragma unroll
        for (int j=0;j<4;++j) acc[r][c][i][j]=0.f;

  for (int kp = 0; kp < K; kp += 16){
    #pragma unroll
    for (int l = 0; l < RM; ++l){
      int li = t + l*256;
      int row = li >> 2, kq = (li & 3) << 2;
      float4 v = *(const float4*)(A + (size_t)(m0+row)*K + kp + kq);
      As[kq+0][row]=v.x; As[kq+1][row]=v.y; As[kq+2][row]=v.z; As[kq+3][row]=v.w;
    }
    #pragma unroll
    for (int l = 0; l < RN; ++l){
      int li = t + l*256;
      int row = li >> 2, kq = (li & 3) << 2;
      int gn = n0 + row;
      float4 v = make_float4(0.f,0.f,0.f,0.f);
      float sc = 1.f;
      if (gn < Brows){
        v = *(const float4*)(B + (size_t)gn*K + kp + kq);
        if (bscale) sc = bscale[gn];
      }
      Bs[kq+0][row]=v.x*sc; Bs[kq+1][row]=v.y*sc; Bs[kq+2][row]=v.z*sc; Bs[kq+3][row]=v.w*sc;
    }
    __syncthreads();
    #pragma unroll
    for (int kk = 0; kk < 16; ++kk){
      float av[RM][4], bv[RN][4];
      #pragma unroll
      for (int r=0;r<RM;++r){
        float4 a = *(const float4*)&As[kk][r*64 + tm*4];
        av[r][0]=a.x; av[r][1]=a.y; av[r][2]=a.z; av[r][3]=a.w;
      }
      #pragma unroll
      for (int c=0;c<RN;++c){
        float4 b = *(const float4*)&Bs[kk][c*64 + tn*4];
        bv[c][0]=b.x; bv[c][1]=b.y; bv[c][2]=b.z; bv[c][3]=b.w;
      }
      #pragma unroll
      for (int r=0;r<RM;++r)
        #pragma unroll
        for (int c=0;c<RN;++c)
          #pragma unroll
          for (int i=0;i<4;++i)
            #pragma unroll
            for (int j=0;j<4;++j)
              acc[r][c][i][j] = fmaf(av[r][i], bv[c][j], acc[r][c][i][j]);
    }
    __syncthreads();
  }

  #pragma unroll
  for (int r=0;r<RM;++r){
    #pragma unroll
    for (int i=0;i<4;++i){
      int gm = m0 + r*64 + tm*4 + i;
      #pragma unroll
      for (int c=0;c<RN;++c){
        int gn = n0 + c*64 + tn*4;
        if (gn >= Nn) continue;
        float* cp = C + (size_t)gm*ldc + gn;
        float o0=acc[r][c][i][0], o1=acc[r][c][i][1], o2=acc[r][c][i][2], o3=acc[r][c][i][3];
        if (gn + 3 < Nn){
          float4 o = make_float4(o0,o1,o2,o3);
          if (bias){ float4 bb = *(const float4*)&bias[gn]; o.x+=bb.x; o.y+=bb.y; o.z+=bb.z; o.w+=bb.w; }
          if (ACCUM){ float4 cc = *(const float4*)cp; o.x+=cc.x; o.y+=cc.y; o.z+=cc.z; o.w+=cc.w; }
          *(float4*)cp = o;
        } else {
          float ov[4] = {o0,o1,o2,o3};
          for (int j=0;j<4;++j){
            if (gn + j < Nn){
              float o = ov[j];
              if (bias)  o += bias[gn+j];
              if (ACCUM) o += cp[j];
              cp[j] = o;
            }
          }
        }
      }
    }
  }
}

// ---------- scores GEMM: bf16x3 split MFMA (unchanged, passing) ----------
__global__ __launch_bounds__(256) void scores_mfma_kernel(
    const float* __restrict__ A, const float* __restrict__ Bm,
    const float* __restrict__ rn, float* __restrict__ C,
    int M, int Nn, int K, int ldc)
{
  __shared__ unsigned short Ah_s[128][40];
  __shared__ unsigned short Al_s[128][40];
  __shared__ unsigned short Bh_s[128][40];
  __shared__ unsigned short Bl_s[128][40];

  const int t = threadIdx.x;
  const int lane = t & 63, wid = t >> 6;
  const int wm = wid >> 1, wn = wid & 1;
  const int l15 = lane & 15, l4 = lane >> 4;
  const int m0 = blockIdx.y * 128, n0 = blockIdx.x * 128;

  f32x4 acc[4][4];
  #pragma unroll
  for (int i=0;i<4;++i)
    #pragma unroll
    for (int j=0;j<4;++j) acc[i][j] = (f32x4)0.f;

  for (int kp = 0; kp < K; kp += 32){
    #pragma unroll
    for (int i = 0; i < 4; ++i){
      int li  = t + i*256;
      int row = li >> 3;
      int kq  = (li & 7) << 2;
      float4 va = *(const float4*)(A + (size_t)(m0+row)*K + kp + kq);
      uint2 hw, lw; pack_hilo(va, hw, lw);
      *(uint2*)&Ah_s[row][kq] = hw;
      *(uint2*)&Al_s[row][kq] = lw;

      int gn = n0 + row;
      float4 vb = make_float4(0.f,0.f,0.f,0.f);
      float sc = 0.f;
      if (gn < Nn){ vb = *(const float4*)(Bm + (size_t)gn*K + kp + kq); sc = rn[gn]; }
      vb.x*=sc; vb.y*=sc; vb.z*=sc; vb.w*=sc;
      pack_hilo(vb, hw, lw);
      *(uint2*)&Bh_s[row][kq] = hw;
      *(uint2*)&Bl_s[row][kq] = lw;
    }
    __syncthreads();

    bf16x8 bh[4], bl[4];
    #pragma unroll
    for (int fn = 0; fn < 4; ++fn){
      int bcol = wn*64 + fn*16 + l15;
      bh[fn] = *(const bf16x8*)&Bh_s[bcol][l4*8];
      bl[fn] = *(const bf16x8*)&Bl_s[bcol][l4*8];
    }
    #pragma unroll
    for (int fm = 0; fm < 4; ++fm){
      int arow = wm*64 + fm*16 + l15;
      bf16x8 ah = *(const bf16x8*)&Ah_s[arow][l4*8];
      bf16x8 al = *(const bf16x8*)&Al_s[arow][l4*8];
      #pragma unroll
      for (int fn = 0; fn < 4; ++fn){
        acc[fm][fn] = __builtin_amdgcn_mfma_f32_16x16x32_bf16(ah, bh[fn], acc[fm][fn], 0,0,0);
        acc[fm][fn] = __builtin_amdgcn_mfma_f32_16x16x32_bf16(ah, bl[fn], acc[fm][fn], 0,0,0);
        acc[fm][fn] = __builtin_amdgcn_mfma_f32_16x16x32_bf16(al, bh[fn], acc[fm][fn], 0,0,0);
      }
    }
    __syncthreads();
  }

  #pragma unroll
  for (int fm = 0; fm < 4; ++fm){
    int row = m0 + wm*64 + fm*16 + l4*4;
    #pragma unroll
    for (int fn = 0; fn < 4; ++fn){
      int col = n0 + wn*64 + fn*16 + l15;
      if (col < Nn){
        float* cp = C + (size_t)row*ldc + col;
        #pragma unroll
        for (int r = 0; r < 4; ++r) cp[(size_t)r*ldc] = acc[fm][fn][r];
      }
    }
  }
}

// ---------- chunk filter: tau-threshold candidate selection ----------
// tau = 32nd largest of 256 per-thread strided maxima. {x >= tau} is a
// guaranteed superset of the chunk top-32 (32 distinct thread maxima >= tau).
// Filter at tau - eps to cover bf16x3 approx error vs exact scores.
__global__ __launch_bounds__(256) void chunk_filter_kernel(
    const float* __restrict__ scores, int ncols, int ldc,
    float* __restrict__ cand_s, int* __restrict__ cand_i,
    int col0, int chunk, int nchunks, int cap, float eps)
{
  __shared__ float sv[256];
  __shared__ float tau_s;
  __shared__ int cnt;
  const int row = blockIdx.x, t = threadIdx.x;
  const float* sr = scores + (size_t)row * ldc;

  // phase 1: per-thread strided max
  float m = -INFINITY;
  for (int j = t; j < ncols; j += 256) m = fmaxf(m, sr[j]);
  sv[t] = m;
  __syncthreads();

  // phase 2: bitonic sort 256 values descending; tau = sv[31]
  for (int k = 2; k <= 256; k <<= 1){
    for (int j = k >> 1; j > 0; j >>= 1){
      int p = t ^ j;
      float a = sv[t], b = sv[p];
      bool up = ((t & k) == 0);
      float keep = (t < p) ? (up ? fmaxf(a,b) : fminf(a,b))
                           : (up ? fminf(a,b) : fmaxf(a,b));
      __syncthreads();
      sv[t] = keep;
      __syncthreads();
    }
  }
  if (t == 0){ tau_s = sv[31]; cnt = 0; }
  __syncthreads();
  const float thr = tau_s - eps;

  float* cs = cand_s + ((size_t)row * nchunks + chunk) * cap;
  int*   ci = cand_i + ((size_t)row * nchunks + chunk) * cap;

  // phase 3: parallel compaction of elements >= thr
  for (int j = t; j < ncols; j += 256){
    float v = sr[j];
    if (v >= thr){
      int pos = atomicAdd(&cnt, 1);
      if (pos < cap){ cs[pos] = v; ci[pos] = col0 + j; }
    }
  }
  __syncthreads();
  int n = cnt < cap ? cnt : cap;
  for (int j = n + t; j < cap; j += 256) ci[j] = -1;
}

// ---------- select: prune (tau-trick on approx) -> fp32 rescore -> sort ----------
__global__ __launch_bounds__(256) void select_softmax_gather_kernel(
    const float* __restrict__ cand_s, const int* __restrict__ cand_i,
    const float* __restrict__ p, const float* __restrict__ rn_bank,
    const float* __restrict__ pnorm, const float* __restrict__ bank,
    float* __restrict__ z, int ncap, int D, int topm, float invtemp, float eps)
{
  __shared__ float p_s[1024];
  __shared__ float vs[1024]; __shared__ int vi[1024];
  __shared__ float sv[256];
  __shared__ int   cidx[256];
  __shared__ float rv[256];
  __shared__ float tau_s;
  __shared__ int cnt;
  const int row = blockIdx.x, t = threadIdx.x;
  const int lane = t & 63, wid = t >> 6;

  // load p row + candidate slots
  const float4* pr = (const float4*)(p + (size_t)row * D);
  for (int i = t; i < (D >> 2); i += 256) ((float4*)p_s)[i] = pr[i];
  const float* cs = cand_s + (size_t)row * ncap;
  const int*  ci = cand_i + (size_t)row * ncap;
  for (int j = t; j < ncap; j += 256){
    int k = ci[j];
    vi[j] = k;
    vs[j] = (k >= 0) ? cs[j] : -INFINITY;
  }
  __syncthreads();

  // phase A: tau'' = 32nd of per-thread maxima over approx candidate scores
  float m = -INFINITY;
  for (int j = t; j < ncap; j += 256) m = fmaxf(m, vs[j]);
  sv[t] = m;
  __syncthreads();
  for (int k = 2; k <= 256; k <<= 1){
    for (int j = k >> 1; j > 0; j >>= 1){
      int pp = t ^ j;
      float a = sv[t], b = sv[pp];
      bool up = ((t & k) == 0);
      float keep = (t < pp) ? (up ? fmaxf(a,b) : fminf(a,b))
                            : (up ? fminf(a,b) : fmaxf(a,b));
      __syncthreads();
      sv[t] = keep;
      __syncthreads();
    }
  }
  if (t == 0){ tau_s = sv[31]; cnt = 0; }
  __syncthreads();
  const float thr = tau_s - eps;

  // phase B: compact candidate indices with approx >= thr (cap 256)
  for (int j = t; j < ncap; j += 256){
    if (vi[j] >= 0 && vs[j] >= thr){
      int pos = atomicAdd(&cnt, 1);
      if (pos < 256) cidx[pos] = vi[j];
    }
  }
  __syncthreads();
  const int n2 = cnt < 256 ? cnt : 256;
  rv[t] = -INFINITY;
  if (t >= n2) cidx[t] = 0x7fffffff;
  __syncthreads();

  // phase C: exact fp32 rescore, one wave per candidate
  const int nj = D >> 8;
  for (int c = wid; c < n2; c += 4){
    int idx = cidx[c];
    const float4* kr = (const float4*)(bank + (size_t)idx * D);
    float ss = 0.f;
    for (int j = 0; j < nj; ++j){
      float4 kv = kr[lane + j*64];
      float4 pv = *(const float4*)&p_s[(lane + j*64) << 2];
      ss = fmaf(pv.x,kv.x, fmaf(pv.y,kv.y, fmaf(pv.z,kv.z, fmaf(pv.w,kv.w, ss))));
    }
    #pragma unroll
    for (int off = 32; off; off >>= 1) ss += __shfl_xor(ss, off);
    if (lane == 0) rv[c] = ss * rn_bank[idx];
  }
  __syncthreads();

  // phase D: bitonic sort 256 (val desc, idx asc) -> top-32 in rv/cidx[0..31]
  for (int k = 2; k <= 256; k <<= 1){
    for (int j = k >> 1; j > 0; j >>= 1){
      int pp = t ^ j;
      float av = rv[t];  int ai = cidx[t];
      float bv = rv[pp]; int bi = cidx[pp];
      bool up = ((t & k) == 0);
      bool agtb = (av > bv) || (av == bv && ai < bi);
      bool keepA = (t < pp) ? (up ? agtb : !agtb)
                            : (up ? !agtb : agtb);
      __syncthreads();
      if (keepA){ rv[t] = av; cidx[t] = ai; } else { rv[t] = bv; cidx[t] = bi; }
      __syncthreads();
    }
  }

  // phase E: softmax over top-32 (fold 1/||p|| and 1/T here) + weighted gather
  if (t == 0){
    float pn = pnorm[row] * invtemp;
    float mx = rv[0] * pn;
    float sum = 0.f;
    for (int i = 0; i < topm; ++i){
      float w = expf(rv[i]*pn - mx);
      sv[i] = w; sum += w;
    }
    float inv = 1.f / sum;
    for (int i = 0; i < topm; ++i) sv[i] *= inv;
  }
  __syncthreads();

  for (int d4 = t; d4 < (D >> 2); d4 += 256){
    float ax=0.f, ay=0.f, az=0.f, aw=0.f;
    for (int i = 0; i < topm; ++i){
      float a = sv[i];
      const float4 v = *(const float4*)(bank + (size_t)cidx[i]*D + (d4<<2));
      ax = fmaf(a, v.x, ax); ay = fmaf(a, v.y, ay);
      az = fmaf(a, v.z, az); aw = fmaf(a, v.w, aw);
    }
    *(float4*)(z + (size_t)row*D + (d4<<2)) = make_float4(ax,ay,az,aw);
  }
}

// ---------- LayerNorm ----------
__global__ __launch_bounds__(256) void layernorm_kernel(
    const float* __restrict__ ref, const float* __restrict__ gamma,
    const float* __restrict__ beta, float* __restrict__ out, int D, float eps)
{
  __shared__ float s1[4], s2[4];
  const int row = blockIdx.x, t = threadIdx.x;
  const float4* xr = (const float4*)(ref + (size_t)row*D);
  int nv = D >> 2;
  float sum = 0.f, ssq = 0.f;
  for (int i = t; i < nv; i += 256){
    float4 v = xr[i];
    sum += v.x+v.y+v.z+v.w;
    ssq = fmaf(v.x,v.x, fmaf(v.y,v.y, fmaf(v.z,v.z, fmaf(v.w,v.w, ssq))));
  }
  const int lane = t & 63, wid = t >> 6;
  #pragma unroll
  for (int off = 32; off; off >>= 1){ sum += __shfl_xor(sum, off); ssq += __shfl_xor(ssq, off); }
  if (lane == 0){ s1[wid] = sum; s2[wid] = ssq; }
  __syncthreads();
  sum = s1[0]+s1[1]+s1[2]+s1[3];
  ssq = s2[0]+s2[1]+s2[2]+s2[3];
  float mu  = sum / (float)D;
  float var = ssq / (float)D - mu*mu;
  float rs  = rsqrtf(var + eps);
  const float4* g4 = (const float4*)gamma;
  const float4* b4 = (const float4*)beta;
  float4* o4 = (float4*)(out + (size_t)row*D);
  for (int i = t; i < nv; i += 256){
    float4 v = xr[i], g = g4[i], bb = b4[i];
    float4 o;
    o.x = (v.x-mu)*rs*g.x + bb.x;
    o.y = (v.y-mu)*rs*g.y + bb.y;
    o.z = (v.z-mu)*rs*g.z + bb.z;
    o.w = (v.w-mu)*rs*g.w + bb.w;
    o4[i] = o;
  }
}

// ---------------------------------------------------------------------------
extern "C" void kernel_launch(void* const* d_in, const int* in_sizes, int n_in,
                              void* d_out, int out_size, void* d_ws, size_t ws_size,
                              hipStream_t stream)
{
  const float* q       = (const float*)d_in[0];
  const float* bank    = (const float*)d_in[1];
  const float* proj_w  = (const float*)d_in[2];
  const float* proj_b  = (const float*)d_in[3];
  const float* unify_w = (const float*)d_in[4];
  const float* unify_b = (const float*)d_in[5];
  const float* gamma   = (const float*)d_in[6];
  const float* beta    = (const float*)d_in[7];

  const int D = in_sizes[6];
  const int B = in_sizes[0] / D;
  const int N = in_sizes[1] / D;
  const int S = in_sizes[2] / (D * D);
  const int TOPM = 32;
  const int CAP  = 64;               // candidate slots per (row,chunk)
  const float INVTEMP = 1.0f / 0.07f;
  const float EPS = 1e-3f;           // >= 2x bf16x3 score error bound (~2e-4)

  // --- workspace sizing (adaptive; ncap must stay <= 1024 for select LDS) ---
  size_t fixed = align256((size_t)N*4) + align256((size_t)B*4) + 3*align256((size_t)B*D*4);
  const int ncopts[3] = {12544, 8192, 6272};
  int NC = 6272;
  for (int ci = 0; ci < 3; ++ci){
    int cand = ncopts[ci];
    int nch = (N + cand - 1) / cand;
    size_t tot = fixed + align256((size_t)B*cand*4) + 2*align256((size_t)B*nch*CAP*4);
    if (tot <= ws_size){ NC = cand; break; }
  }
  const int NCH = (N + NC - 1) / NC;

  char* wsb = (char*)d_ws;
  size_t off = 0;
  auto take = [&](size_t bytes)->char*{ char* p = wsb + off; off += align256(bytes); return p; };
  float* rn_bank = (float*)take((size_t)N*4);
  float* pnorm   = (float*)take((size_t)B*4);
  float* p       = (float*)take((size_t)B*D*4);
  float* z       = (float*)take((size_t)B*D*4);
  float* ref     = (float*)take((size_t)B*D*4);
  float* scores  = (float*)take((size_t)B*NC*4);
  float* cand_s  = (float*)take((size_t)B*NCH*CAP*4);
  int*   cand_i  = (int*)  take((size_t)B*NCH*CAP*4);

  // 1) bank key inverse norms
  row_rnorm_kernel<<<(N+3)/4, 256, 0, stream>>>(bank, rn_bank, N, D);

  for (int s = 0; s < S; ++s){
    // 2) p = q @ proj_w[s]^T + proj_b[s]
    dim3 g1(D/64, B/64);
    gemm_nt_kernel<1,1,false><<<g1, 256, 0, stream>>>(
        q, proj_w + (size_t)s*D*D, proj_b + (size_t)s*D, nullptr,
        p, B, D, D, D, D);
    // 3) ||p|| row norms
    row_rnorm_kernel<<<(B+3)/4, 256, 0, stream>>>(p, pnorm, B, D);

    // 4) chunked approx scores + tau-filter candidates
    for (int c = 0; c < NCH; ++c){
      int n0 = c * NC;
      int nv = N - n0; if (nv > NC) nv = NC;
      dim3 g2((nv + 127)/128, B/128);
      scores_mfma_kernel<<<g2, 256, 0, stream>>>(
          p, bank + (size_t)n0*D, rn_bank + n0,
          scores, B, nv, D, NC);
      chunk_filter_kernel<<<B, 256, 0, stream>>>(
          scores, nv, NC, cand_s, cand_i, n0, c, NCH, CAP, EPS);
    }

    // 5) prune + fp32 rescore + exact top-32 + softmax + gather
    select_softmax_gather_kernel<<<B, 256, 0, stream>>>(
        cand_s, cand_i, p, rn_bank, pnorm, bank, z,
        NCH*CAP, D, TOPM, INVTEMP, EPS);

    // 6) ref (+)= z @ unify_w[s]^T + unify_b[s]
    if (s == 0)
      gemm_nt_kernel<1,1,false><<<g1, 256, 0, stream>>>(
          z, unify_w + (size_t)s*D*D, unify_b + (size_t)s*D, nullptr,
          ref, B, D, D, D, D);
    else
      gemm_nt_kernel<1,1,true><<<g1, 256, 0, stream>>>(
          z, unify_w + (size_t)s*D*D, unify_b + (size_t)s*D, nullptr,
          ref, B, D, D, D, D);
  }

  // 7) LayerNorm -> out
  layernorm_kernel<<<B, 256, 0, stream>>>(ref, gamma, beta, (float*)d_out, D, 1e-5f);
}

// Round 7
// 3520.625 us; speedup vs baseline: 3.5069x; 1.1988x over previous
//
#include <hip/hip_runtime.h>
#include <math.h>

// ---------------------------------------------------------------------------
// MultiScaleRetriever round 7: R6 pipeline (tau-filter + fp32 rescore, passing)
// + 256x256 8-wave swizzled scores kernel (R2's math, vetted by the
// identical-absmax equivalence R2==R3; selection guarded by rescore).
// ---------------------------------------------------------------------------

static inline size_t align256(size_t x){ return (x + 255) & ~size_t(255); }

typedef short bf16x8 __attribute__((ext_vector_type(8)));
typedef float f32x4  __attribute__((ext_vector_type(4)));

__device__ inline unsigned short f2bf(float f){
  unsigned int u = __float_as_uint(f);
  u += 0x7fffu + ((u >> 16) & 1u);
  return (unsigned short)(u >> 16);
}
__device__ inline float bf2f(unsigned short h){
  return __uint_as_float(((unsigned int)h) << 16);
}
__device__ inline void pack_hilo(float4 v, uint2& hw, uint2& lw){
  unsigned short h0=f2bf(v.x), h1=f2bf(v.y), h2=f2bf(v.z), h3=f2bf(v.w);
  unsigned short g0=f2bf(v.x-bf2f(h0)), g1=f2bf(v.y-bf2f(h1)),
                 g2=f2bf(v.z-bf2f(h2)), g3=f2bf(v.w-bf2f(h3));
  hw.x = (unsigned)h0 | ((unsigned)h1<<16); hw.y = (unsigned)h2 | ((unsigned)h3<<16);
  lw.x = (unsigned)g0 | ((unsigned)g1<<16); lw.y = (unsigned)g2 | ((unsigned)g3<<16);
}

// ---------- per-row 1/max(||x||,1e-12) ----------
__global__ __launch_bounds__(256) void row_rnorm_kernel(
    const float* __restrict__ X, float* __restrict__ rn, int rows, int D)
{
  int wv = threadIdx.x >> 6, lane = threadIdx.x & 63;
  int r = blockIdx.x * 4 + wv;
  if (r >= rows) return;
  const float4* xr = (const float4*)(X + (size_t)r * D);
  int nv = D >> 2;
  float ss = 0.f;
  for (int i = lane; i < nv; i += 64){
    float4 v = xr[i];
    ss = fmaf(v.x,v.x, fmaf(v.y,v.y, fmaf(v.z,v.z, fmaf(v.w,v.w, ss))));
  }
  #pragma unroll
  for (int off = 32; off; off >>= 1) ss += __shfl_xor(ss, off);
  if (lane == 0) rn[r] = 1.f / fmaxf(sqrtf(ss), 1e-12f);
}

// ---------- fp32 NT GEMM (proj/unify) ----------
template<int RM, int RN, bool ACCUM>
__global__ __launch_bounds__(256) void gemm_nt_kernel(
    const float* __restrict__ A, const float* __restrict__ B,
    const float* __restrict__ bias, const float* __restrict__ bscale,
    float* __restrict__ C, int M, int Nn, int K, int Brows, int ldc)
{
  __shared__ float As[16][RM*64 + 4];
  __shared__ float Bs[16][RN*64 + 4];
  const int t  = threadIdx.x;
  const int tm = t >> 4, tn = t & 15;
  const int m0 = blockIdx.y * (RM*64), n0 = blockIdx.x * (RN*64);

  float acc[RM][RN][4][4];
  #pragma unroll
  for (int r=0;r<RM;++r)
    #pragma unroll
    for (int c=0;c<RN;++c)
      #pragma unroll
      for (int i=0;i<4;++i)
        #pragma unroll
        for (int j=0;j<4;++j) acc[r][c][i][j]=0.f;

  for (int kp = 0; kp < K; kp += 16){
    #pragma unroll
    for (int l = 0; l < RM; ++l){
      int li = t + l*256;
      int row = li >> 2, kq = (li & 3) << 2;
      float4 v = *(const float4*)(A + (size_t)(m0+row)*K + kp + kq);
      As[kq+0][row]=v.x; As[kq+1][row]=v.y; As[kq+2][row]=v.z; As[kq+3][row]=v.w;
    }
    #pragma unroll
    for (int l = 0; l < RN; ++l){
      int li = t + l*256;
      int row = li >> 2, kq = (li & 3) << 2;
      int gn = n0 + row;
      float4 v = make_float4(0.f,0.f,0.f,0.f);
      float sc = 1.f;
      if (gn < Brows){
        v = *(const float4*)(B + (size_t)gn*K + kp + kq);
        if (bscale) sc = bscale[gn];
      }
      Bs[kq+0][row]=v.x*sc; Bs[kq+1][row]=v.y*sc; Bs[kq+2][row]=v.z*sc; Bs[kq+3][row]=v.w*sc;
    }
    __syncthreads();
    #pragma unroll
    for (int kk = 0; kk < 16; ++kk){
      float av[RM][4], bv[RN][4];
      #pragma unroll
      for (int r=0;r<RM;++r){
        float4 a = *(const float4*)&As[kk][r*64 + tm*4];
        av[r][0]=a.x; av[r][1]=a.y; av[r][2]=a.z; av[r][3]=a.w;
      }
      #pragma unroll
      for (int c=0;c<RN;++c){
        float4 b = *(const float4*)&Bs[kk][c*64 + tn*4];
        bv[c][0]=b.x; bv[c][1]=b.y; bv[c][2]=b.z; bv[c][3]=b.w;
      }
      #pragma unroll
      for (int r=0;r<RM;++r)
        #pragma unroll
        for (int c=0;c<RN;++c)
          #pragma unroll
          for (int i=0;i<4;++i)
            #pragma unroll
            for (int j=0;j<4;++j)
              acc[r][c][i][j] = fmaf(av[r][i], bv[c][j], acc[r][c][i][j]);
    }
    __syncthreads();
  }

  #pragma unroll
  for (int r=0;r<RM;++r){
    #pragma unroll
    for (int i=0;i<4;++i){
      int gm = m0 + r*64 + tm*4 + i;
      #pragma unroll
      for (int c=0;c<RN;++c){
        int gn = n0 + c*64 + tn*4;
        if (gn >= Nn) continue;
        float* cp = C + (size_t)gm*ldc + gn;
        float o0=acc[r][c][i][0], o1=acc[r][c][i][1], o2=acc[r][c][i][2], o3=acc[r][c][i][3];
        if (gn + 3 < Nn){
          float4 o = make_float4(o0,o1,o2,o3);
          if (bias){ float4 bb = *(const float4*)&bias[gn]; o.x+=bb.x; o.y+=bb.y; o.z+=bb.z; o.w+=bb.w; }
          if (ACCUM){ float4 cc = *(const float4*)cp; o.x+=cc.x; o.y+=cc.y; o.z+=cc.z; o.w+=cc.w; }
          *(float4*)cp = o;
        } else {
          float ov[4] = {o0,o1,o2,o3};
          for (int j=0;j<4;++j){
            if (gn + j < Nn){
              float o = ov[j];
              if (bias)  o += bias[gn+j];
              if (ACCUM) o += cp[j];
              cp[j] = o;
            }
          }
        }
      }
    }
  }
}

// ---------- scores GEMM: bf16x3 split MFMA, 256x256 tile, 8 waves ----------
// C[m,n] = sum_k A[m,k]*B[n,k]*rn[n] ~= Ah*Bh + Ah*Bl + Al*Bh (fp32 acc).
// BM=BN=256, BK=32. 512 threads = 8 waves (2M x 4N), wave tile 128x64.
// LDS row = 128 B [hi:64 | lo:64], byte offsets XOR'd with ((row&7)<<4);
// writer and reader apply the same XOR -> self-consistent permutation that
// spreads banks (verified on paper R3; math identical to R3's passing kernel).
__global__ __launch_bounds__(512, 2) void scores_mfma_kernel(
    const float* __restrict__ A, const float* __restrict__ Bm,
    const float* __restrict__ rn, float* __restrict__ C,
    int M, int Nn, int K, int ldc)
{
  __shared__ __align__(16) unsigned char smem[65536];   // A: [0,32K), B: [32K,64K)
  unsigned char* As = smem;
  unsigned char* Bs = smem + 32768;

  const int t = threadIdx.x;
  const int lane = t & 63, wid = t >> 6;
  const int wm = wid >> 2, wn = wid & 3;       // 2 x 4 wave grid
  const int l15 = lane & 15, l4 = lane >> 4;
  const int m0 = blockIdx.y * 256, n0 = blockIdx.x * 256;

  f32x4 acc[8][4];
  #pragma unroll
  for (int i=0;i<8;++i)
    #pragma unroll
    for (int j=0;j<4;++j) acc[i][j] = (f32x4)0.f;

  const int srow = t >> 3;          // base row for i=0 (rows advance by 64 per i)
  const int skq  = (t & 7) * 4;     // element offset within BK=32

  for (int kp = 0; kp < K; kp += 32){
    // ---- stage A tile (256x32 fp32 -> hi/lo bf16) ----
    #pragma unroll
    for (int i = 0; i < 4; ++i){
      int row = srow + i*64;
      float4 v = *(const float4*)(A + (size_t)(m0+row)*K + kp + skq);
      uint2 hw, lw; pack_hilo(v, hw, lw);
      int xr = (row & 7) << 4;
      *(uint2*)(As + row*128 + (( skq*2      ) ^ xr)) = hw;
      *(uint2*)(As + row*128 + ((64 + skq*2 ) ^ xr)) = lw;
    }
    // ---- stage B tile (bank rows, scaled by rn) ----
    #pragma unroll
    for (int i = 0; i < 4; ++i){
      int row = srow + i*64;
      int gn = n0 + row;
      float4 v = make_float4(0.f,0.f,0.f,0.f);
      float sc = 0.f;
      if (gn < Nn){ v = *(const float4*)(Bm + (size_t)gn*K + kp + skq); sc = rn[gn]; }
      v.x *= sc; v.y *= sc; v.z *= sc; v.w *= sc;
      uint2 hw, lw; pack_hilo(v, hw, lw);
      int xr = (row & 7) << 4;
      *(uint2*)(Bs + row*128 + (( skq*2      ) ^ xr)) = hw;
      *(uint2*)(Bs + row*128 + ((64 + skq*2 ) ^ xr)) = lw;
    }
    __syncthreads();

    // ---- compute: load B frags once, stream A frags ----
    bf16x8 Bh[4], Bl[4];
    #pragma unroll
    for (int fn = 0; fn < 4; ++fn){
      int brow = wn*64 + fn*16 + l15;
      int xr = (brow & 7) << 4;
      const unsigned char* bp = Bs + brow*128;
      Bh[fn] = *(const bf16x8*)(bp + (( l4*16      ) ^ xr));
      Bl[fn] = *(const bf16x8*)(bp + ((64 + l4*16 ) ^ xr));
    }
    #pragma unroll
    for (int fm = 0; fm < 8; ++fm){
      int arow = wm*128 + fm*16 + l15;
      int xr = (arow & 7) << 4;
      const unsigned char* ap = As + arow*128;
      bf16x8 Ah = *(const bf16x8*)(ap + (( l4*16      ) ^ xr));
      bf16x8 Al = *(const bf16x8*)(ap + ((64 + l4*16 ) ^ xr));
      #pragma unroll
      for (int fn = 0; fn < 4; ++fn){
        acc[fm][fn] = __builtin_amdgcn_mfma_f32_16x16x32_bf16(Ah, Bh[fn], acc[fm][fn], 0,0,0);
        acc[fm][fn] = __builtin_amdgcn_mfma_f32_16x16x32_bf16(Ah, Bl[fn], acc[fm][fn], 0,0,0);
        acc[fm][fn] = __builtin_amdgcn_mfma_f32_16x16x32_bf16(Al, Bh[fn], acc[fm][fn], 0,0,0);
      }
    }
    __syncthreads();
  }

  // ---- store: C/D layout col=lane&15, row=(lane>>4)*4+reg ----
  #pragma unroll
  for (int fm = 0; fm < 8; ++fm){
    int row = m0 + wm*128 + fm*16 + l4*4;
    #pragma unroll
    for (int fn = 0; fn < 4; ++fn){
      int col = n0 + wn*64 + fn*16 + l15;
      if (col < Nn){
        float* cp = C + (size_t)row*ldc + col;
        #pragma unroll
        for (int r = 0; r < 4; ++r) cp[(size_t)r*ldc] = acc[fm][fn][r];
      }
    }
  }
}

// ---------- chunk filter: tau-threshold candidate selection ----------
__global__ __launch_bounds__(256) void chunk_filter_kernel(
    const float* __restrict__ scores, int ncols, int ldc,
    float* __restrict__ cand_s, int* __restrict__ cand_i,
    int col0, int chunk, int nchunks, int cap, float eps)
{
  __shared__ float sv[256];
  __shared__ float tau_s;
  __shared__ int cnt;
  const int row = blockIdx.x, t = threadIdx.x;
  const float* sr = scores + (size_t)row * ldc;

  float m = -INFINITY;
  for (int j = t; j < ncols; j += 256) m = fmaxf(m, sr[j]);
  sv[t] = m;
  __syncthreads();

  for (int k = 2; k <= 256; k <<= 1){
    for (int j = k >> 1; j > 0; j >>= 1){
      int p = t ^ j;
      float a = sv[t], b = sv[p];
      bool up = ((t & k) == 0);
      float keep = (t < p) ? (up ? fmaxf(a,b) : fminf(a,b))
                           : (up ? fminf(a,b) : fmaxf(a,b));
      __syncthreads();
      sv[t] = keep;
      __syncthreads();
    }
  }
  if (t == 0){ tau_s = sv[31]; cnt = 0; }
  __syncthreads();
  const float thr = tau_s - eps;

  float* cs = cand_s + ((size_t)row * nchunks + chunk) * cap;
  int*   ci = cand_i + ((size_t)row * nchunks + chunk) * cap;

  for (int j = t; j < ncols; j += 256){
    float v = sr[j];
    if (v >= thr){
      int pos = atomicAdd(&cnt, 1);
      if (pos < cap){ cs[pos] = v; ci[pos] = col0 + j; }
    }
  }
  __syncthreads();
  int n = cnt < cap ? cnt : cap;
  for (int j = n + t; j < cap; j += 256) ci[j] = -1;
}

// ---------- select: prune (tau-trick on approx) -> fp32 rescore -> sort ----------
__global__ __launch_bounds__(256) void select_softmax_gather_kernel(
    const float* __restrict__ cand_s, const int* __restrict__ cand_i,
    const float* __restrict__ p, const float* __restrict__ rn_bank,
    const float* __restrict__ pnorm, const float* __restrict__ bank,
    float* __restrict__ z, int ncap, int D, int topm, float invtemp, float eps)
{
  __shared__ float p_s[1024];
  __shared__ float vs[1024]; __shared__ int vi[1024];
  __shared__ float sv[256];
  __shared__ int   cidx[256];
  __shared__ float rv[256];
  __shared__ float tau_s;
  __shared__ int cnt;
  const int row = blockIdx.x, t = threadIdx.x;
  const int lane = t & 63, wid = t >> 6;

  const float4* pr = (const float4*)(p + (size_t)row * D);
  for (int i = t; i < (D >> 2); i += 256) ((float4*)p_s)[i] = pr[i];
  const float* cs = cand_s + (size_t)row * ncap;
  const int*  ci = cand_i + (size_t)row * ncap;
  for (int j = t; j < ncap; j += 256){
    int k = ci[j];
    vi[j] = k;
    vs[j] = (k >= 0) ? cs[j] : -INFINITY;
  }
  __syncthreads();

  float m = -INFINITY;
  for (int j = t; j < ncap; j += 256) m = fmaxf(m, vs[j]);
  sv[t] = m;
  __syncthreads();
  for (int k = 2; k <= 256; k <<= 1){
    for (int j = k >> 1; j > 0; j >>= 1){
      int pp = t ^ j;
      float a = sv[t], b = sv[pp];
      bool up = ((t & k) == 0);
      float keep = (t < pp) ? (up ? fmaxf(a,b) : fminf(a,b))
                            : (up ? fminf(a,b) : fmaxf(a,b));
      __syncthreads();
      sv[t] = keep;
      __syncthreads();
    }
  }
  if (t == 0){ tau_s = sv[31]; cnt = 0; }
  __syncthreads();
  const float thr = tau_s - eps;

  for (int j = t; j < ncap; j += 256){
    if (vi[j] >= 0 && vs[j] >= thr){
      int pos = atomicAdd(&cnt, 1);
      if (pos < 256) cidx[pos] = vi[j];
    }
  }
  __syncthreads();
  const int n2 = cnt < 256 ? cnt : 256;
  rv[t] = -INFINITY;
  if (t >= n2) cidx[t] = 0x7fffffff;
  __syncthreads();

  const int nj = D >> 8;
  for (int c = wid; c < n2; c += 4){
    int idx = cidx[c];
    const float4* kr = (const float4*)(bank + (size_t)idx * D);
    float ss = 0.f;
    for (int j = 0; j < nj; ++j){
      float4 kv = kr[lane + j*64];
      float4 pv = *(const float4*)&p_s[(lane + j*64) << 2];
      ss = fmaf(pv.x,kv.x, fmaf(pv.y,kv.y, fmaf(pv.z,kv.z, fmaf(pv.w,kv.w, ss))));
    }
    #pragma unroll
    for (int off = 32; off; off >>= 1) ss += __shfl_xor(ss, off);
    if (lane == 0) rv[c] = ss * rn_bank[idx];
  }
  __syncthreads();

  for (int k = 2; k <= 256; k <<= 1){
    for (int j = k >> 1; j > 0; j >>= 1){
      int pp = t ^ j;
      float av = rv[t];  int ai = cidx[t];
      float bv = rv[pp]; int bi = cidx[pp];
      bool up = ((t & k) == 0);
      bool agtb = (av > bv) || (av == bv && ai < bi);
      bool keepA = (t < pp) ? (up ? agtb : !agtb)
                            : (up ? !agtb : agtb);
      __syncthreads();
      if (keepA){ rv[t] = av; cidx[t] = ai; } else { rv[t] = bv; cidx[t] = bi; }
      __syncthreads();
    }
  }

  if (t == 0){
    float pn = pnorm[row] * invtemp;
    float mx = rv[0] * pn;
    float sum = 0.f;
    for (int i = 0; i < topm; ++i){
      float w = expf(rv[i]*pn - mx);
      sv[i] = w; sum += w;
    }
    float inv = 1.f / sum;
    for (int i = 0; i < topm; ++i) sv[i] *= inv;
  }
  __syncthreads();

  for (int d4 = t; d4 < (D >> 2); d4 += 256){
    float ax=0.f, ay=0.f, az=0.f, aw=0.f;
    for (int i = 0; i < topm; ++i){
      float a = sv[i];
      const float4 v = *(const float4*)(bank + (size_t)cidx[i]*D + (d4<<2));
      ax = fmaf(a, v.x, ax); ay = fmaf(a, v.y, ay);
      az = fmaf(a, v.z, az); aw = fmaf(a, v.w, aw);
    }
    *(float4*)(z + (size_t)row*D + (d4<<2)) = make_float4(ax,ay,az,aw);
  }
}

// ---------- LayerNorm ----------
__global__ __launch_bounds__(256) void layernorm_kernel(
    const float* __restrict__ ref, const float* __restrict__ gamma,
    const float* __restrict__ beta, float* __restrict__ out, int D, float eps)
{
  __shared__ float s1[4], s2[4];
  const int row = blockIdx.x, t = threadIdx.x;
  const float4* xr = (const float4*)(ref + (size_t)row*D);
  int nv = D >> 2;
  float sum = 0.f, ssq = 0.f;
  for (int i = t; i < nv; i += 256){
    float4 v = xr[i];
    sum += v.x+v.y+v.z+v.w;
    ssq = fmaf(v.x,v.x, fmaf(v.y,v.y, fmaf(v.z,v.z, fmaf(v.w,v.w, ssq))));
  }
  const int lane = t & 63, wid = t >> 6;
  #pragma unroll
  for (int off = 32; off; off >>= 1){ sum += __shfl_xor(sum, off); ssq += __shfl_xor(ssq, off); }
  if (lane == 0){ s1[wid] = sum; s2[wid] = ssq; }
  __syncthreads();
  sum = s1[0]+s1[1]+s1[2]+s1[3];
  ssq = s2[0]+s2[1]+s2[2]+s2[3];
  float mu  = sum / (float)D;
  float var = ssq / (float)D - mu*mu;
  float rs  = rsqrtf(var + eps);
  const float4* g4 = (const float4*)gamma;
  const float4* b4 = (const float4*)beta;
  float4* o4 = (float4*)(out + (size_t)row*D);
  for (int i = t; i < nv; i += 256){
    float4 v = xr[i], g = g4[i], bb = b4[i];
    float4 o;
    o.x = (v.x-mu)*rs*g.x + bb.x;
    o.y = (v.y-mu)*rs*g.y + bb.y;
    o.z = (v.z-mu)*rs*g.z + bb.z;
    o.w = (v.w-mu)*rs*g.w + bb.w;
    o4[i] = o;
  }
}

// ---------------------------------------------------------------------------
extern "C" void kernel_launch(void* const* d_in, const int* in_sizes, int n_in,
                              void* d_out, int out_size, void* d_ws, size_t ws_size,
                              hipStream_t stream)
{
  const float* q       = (const float*)d_in[0];
  const float* bank    = (const float*)d_in[1];
  const float* proj_w  = (const float*)d_in[2];
  const float* proj_b  = (const float*)d_in[3];
  const float* unify_w = (const float*)d_in[4];
  const float* unify_b = (const float*)d_in[5];
  const float* gamma   = (const float*)d_in[6];
  const float* beta    = (const float*)d_in[7];

  const int D = in_sizes[6];
  const int B = in_sizes[0] / D;
  const int N = in_sizes[1] / D;
  const int S = in_sizes[2] / (D * D);
  const int TOPM = 32;
  const int CAP  = 64;               // candidate slots per (row,chunk)
  const float INVTEMP = 1.0f / 0.07f;
  const float EPS = 1e-3f;           // >= 2x bf16x3 score error bound (~2e-4)

  // --- workspace sizing (adaptive; ncap must stay <= 1024 for select LDS) ---
  size_t fixed = align256((size_t)N*4) + align256((size_t)B*4) + 3*align256((size_t)B*D*4);
  const int ncopts[3] = {12544, 8192, 6272};
  int NC = 6272;
  for (int ci = 0; ci < 3; ++ci){
    int cand = ncopts[ci];
    int nch = (N + cand - 1) / cand;
    size_t tot = fixed + align256((size_t)B*cand*4) + 2*align256((size_t)B*nch*CAP*4);
    if (tot <= ws_size){ NC = cand; break; }
  }
  const int NCH = (N + NC - 1) / NC;

  char* wsb = (char*)d_ws;
  size_t off = 0;
  auto take = [&](size_t bytes)->char*{ char* p = wsb + off; off += align256(bytes); return p; };
  float* rn_bank = (float*)take((size_t)N*4);
  float* pnorm   = (float*)take((size_t)B*4);
  float* p       = (float*)take((size_t)B*D*4);
  float* z       = (float*)take((size_t)B*D*4);
  float* ref     = (float*)take((size_t)B*D*4);
  float* scores  = (float*)take((size_t)B*NC*4);
  float* cand_s  = (float*)take((size_t)B*NCH*CAP*4);
  int*   cand_i  = (int*)  take((size_t)B*NCH*CAP*4);

  // 1) bank key inverse norms
  row_rnorm_kernel<<<(N+3)/4, 256, 0, stream>>>(bank, rn_bank, N, D);

  for (int s = 0; s < S; ++s){
    // 2) p = q @ proj_w[s]^T + proj_b[s]
    dim3 g1(D/64, B/64);
    gemm_nt_kernel<1,1,false><<<g1, 256, 0, stream>>>(
        q, proj_w + (size_t)s*D*D, proj_b + (size_t)s*D, nullptr,
        p, B, D, D, D, D);
    // 3) ||p|| row norms
    row_rnorm_kernel<<<(B+3)/4, 256, 0, stream>>>(p, pnorm, B, D);

    // 4) chunked approx scores (256^2 8-wave MFMA) + tau-filter candidates
    for (int c = 0; c < NCH; ++c){
      int n0 = c * NC;
      int nv = N - n0; if (nv > NC) nv = NC;
      dim3 g2((nv + 255)/256, B/256);
      scores_mfma_kernel<<<g2, 512, 0, stream>>>(
          p, bank + (size_t)n0*D, rn_bank + n0,
          scores, B, nv, D, NC);
      chunk_filter_kernel<<<B, 256, 0, stream>>>(
          scores, nv, NC, cand_s, cand_i, n0, c, NCH, CAP, EPS);
    }

    // 5) prune + fp32 rescore + exact top-32 + softmax + gather
    select_softmax_gather_kernel<<<B, 256, 0, stream>>>(
        cand_s, cand_i, p, rn_bank, pnorm, bank, z,
        NCH*CAP, D, TOPM, INVTEMP, EPS);

    // 6) ref (+)= z @ unify_w[s]^T + unify_b[s]
    if (s == 0)
      gemm_nt_kernel<1,1,false><<<g1, 256, 0, stream>>>(
          z, unify_w + (size_t)s*D*D, unify_b + (size_t)s*D, nullptr,
          ref, B, D, D, D, D);
    else
      gemm_nt_kernel<1,1,true><<<g1, 256, 0, stream>>>(
          z, unify_w + (size_t)s*D*D, unify_b + (size_t)s*D, nullptr,
          ref, B, D, D, D, D);
  }

  // 7) LayerNorm -> out
  layernorm_kernel<<<B, 256, 0, stream>>>(ref, gamma, beta, (float*)d_out, D, 1e-5f);
}

// Round 8
// 2334.690 us; speedup vs baseline: 5.2883x; 1.5080x over previous
//
#include <hip/hip_runtime.h>
#include <math.h>

// ---------------------------------------------------------------------------
// MultiScaleRetriever round 8: plain-bf16 approx scores (1 product instead of
// hi/lo x3) under the tau-filter + fp32-rescore umbrella. EPS widened to 0.025
// (>= 2x the 7e-3 max bf16 score error; superset guarantee preserved).
// Scores kernel: same 256x256/8-wave/XOR-swizzle structure as R7, but the
// 128B LDS row now holds k-half0|k-half1 of a BK=64 step (was hi|lo of BK=32):
// 2 MFMAs per (fm,fn) per iter, half the iterations, half the conversion VALU.
// Everything else byte-identical to passing R7.
// ---------------------------------------------------------------------------

static inline size_t align256(size_t x){ return (x + 255) & ~size_t(255); }

typedef short bf16x8 __attribute__((ext_vector_type(8)));
typedef float f32x4  __attribute__((ext_vector_type(4)));

__device__ inline unsigned short f2bf(float f){
  unsigned int u = __float_as_uint(f);
  u += 0x7fffu + ((u >> 16) & 1u);
  return (unsigned short)(u >> 16);
}
__device__ inline uint2 pack_bf4(float4 v){
  uint2 w;
  w.x = (unsigned)f2bf(v.x) | ((unsigned)f2bf(v.y) << 16);
  w.y = (unsigned)f2bf(v.z) | ((unsigned)f2bf(v.w) << 16);
  return w;
}

// ---------- per-row 1/max(||x||,1e-12) ----------
__global__ __launch_bounds__(256) void row_rnorm_kernel(
    const float* __restrict__ X, float* __restrict__ rn, int rows, int D)
{
  int wv = threadIdx.x >> 6, lane = threadIdx.x & 63;
  int r = blockIdx.x * 4 + wv;
  if (r >= rows) return;
  const float4* xr = (const float4*)(X + (size_t)r * D);
  int nv = D >> 2;
  float ss = 0.f;
  for (int i = lane; i < nv; i += 64){
    float4 v = xr[i];
    ss = fmaf(v.x,v.x, fmaf(v.y,v.y, fmaf(v.z,v.z, fmaf(v.w,v.w, ss))));
  }
  #pragma unroll
  for (int off = 32; off; off >>= 1) ss += __shfl_xor(ss, off);
  if (lane == 0) rn[r] = 1.f / fmaxf(sqrtf(ss), 1e-12f);
}

// ---------- fp32 NT GEMM (proj/unify) ----------
template<int RM, int RN, bool ACCUM>
__global__ __launch_bounds__(256) void gemm_nt_kernel(
    const float* __restrict__ A, const float* __restrict__ B,
    const float* __restrict__ bias, const float* __restrict__ bscale,
    float* __restrict__ C, int M, int Nn, int K, int Brows, int ldc)
{
  __shared__ float As[16][RM*64 + 4];
  __shared__ float Bs[16][RN*64 + 4];
  const int t  = threadIdx.x;
  const int tm = t >> 4, tn = t & 15;
  const int m0 = blockIdx.y * (RM*64), n0 = blockIdx.x * (RN*64);

  float acc[RM][RN][4][4];
  #pragma unroll
  for (int r=0;r<RM;++r)
    #pragma unroll
    for (int c=0;c<RN;++c)
      #pragma unroll
      for (int i=0;i<4;++i)
        #pragma unroll
        for (int j=0;j<4;++j) acc[r][c][i][j]=0.f;

  for (int kp = 0; kp < K; kp += 16){
    #pragma unroll
    for (int l = 0; l < RM; ++l){
      int li = t + l*256;
      int row = li >> 2, kq = (li & 3) << 2;
      float4 v = *(const float4*)(A + (size_t)(m0+row)*K + kp + kq);
      As[kq+0][row]=v.x; As[kq+1][row]=v.y; As[kq+2][row]=v.z; As[kq+3][row]=v.w;
    }
    #pragma unroll
    for (int l = 0; l < RN; ++l){
      int li = t + l*256;
      int row = li >> 2, kq = (li & 3) << 2;
      int gn = n0 + row;
      float4 v = make_float4(0.f,0.f,0.f,0.f);
      float sc = 1.f;
      if (gn < Brows){
        v = *(const float4*)(B + (size_t)gn*K + kp + kq);
        if (bscale) sc = bscale[gn];
      }
      Bs[kq+0][row]=v.x*sc; Bs[kq+1][row]=v.y*sc; Bs[kq+2][row]=v.z*sc; Bs[kq+3][row]=v.w*sc;
    }
    __syncthreads();
    #pragma unroll
    for (int kk = 0; kk < 16; ++kk){
      float av[RM][4], bv[RN][4];
      #pragma unroll
      for (int r=0;r<RM;++r){
        float4 a = *(const float4*)&As[kk][r*64 + tm*4];
        av[r][0]=a.x; av[r][1]=a.y; av[r][2]=a.z; av[r][3]=a.w;
      }
      #pragma unroll
      for (int c=0;c<RN;++c){
        float4 b = *(const float4*)&Bs[kk][c*64 + tn*4];
        bv[c][0]=b.x; bv[c][1]=b.y; bv[c][2]=b.z; bv[c][3]=b.w;
      }
      #pragma unroll
      for (int r=0;r<RM;++r)
        #pragma unroll
        for (int c=0;c<RN;++c)
          #pragma unroll
          for (int i=0;i<4;++i)
            #pragma unroll
            for (int j=0;j<4;++j)
              acc[r][c][i][j] = fmaf(av[r][i], bv[c][j], acc[r][c][i][j]);
    }
    __syncthreads();
  }

  #pragma unroll
  for (int r=0;r<RM;++r){
    #pragma unroll
    for (int i=0;i<4;++i){
      int gm = m0 + r*64 + tm*4 + i;
      #pragma unroll
      for (int c=0;c<RN;++c){
        int gn = n0 + c*64 + tn*4;
        if (gn >= Nn) continue;
        float* cp = C + (size_t)gm*ldc + gn;
        float o0=acc[r][c][i][0], o1=acc[r][c][i][1], o2=acc[r][c][i][2], o3=acc[r][c][i][3];
        if (gn + 3 < Nn){
          float4 o = make_float4(o0,o1,o2,o3);
          if (bias){ float4 bb = *(const float4*)&bias[gn]; o.x+=bb.x; o.y+=bb.y; o.z+=bb.z; o.w+=bb.w; }
          if (ACCUM){ float4 cc = *(const float4*)cp; o.x+=cc.x; o.y+=cc.y; o.z+=cc.z; o.w+=cc.w; }
          *(float4*)cp = o;
        } else {
          float ov[4] = {o0,o1,o2,o3};
          for (int j=0;j<4;++j){
            if (gn + j < Nn){
              float o = ov[j];
              if (bias)  o += bias[gn+j];
              if (ACCUM) o += cp[j];
              cp[j] = o;
            }
          }
        }
      }
    }
  }
}

// ---------- scores GEMM: plain bf16 MFMA, BK=64, 256x256 tile, 8 waves ----------
// C[m,n] ~= sum_k bf16(A[m,k]) * bf16(B[n,k]*rn[n])  (fp32 acc).
// 512 threads = 8 waves (2M x 4N), wave tile 128x64. LDS row = 128 B holding
// 64 bf16 k-elements [half0:64B | half1:64B]; byte offsets XOR'd ((row&7)<<4)
// on BOTH write and read (same involution as R7's vetted layout).
__global__ __launch_bounds__(512, 2) void scores_mfma_kernel(
    const float* __restrict__ A, const float* __restrict__ Bm,
    const float* __restrict__ rn, float* __restrict__ C,
    int M, int Nn, int K, int ldc)
{
  __shared__ __align__(16) unsigned char smem[65536];   // A: [0,32K), B: [32K,64K)
  unsigned char* As = smem;
  unsigned char* Bs = smem + 32768;

  const int t = threadIdx.x;
  const int lane = t & 63, wid = t >> 6;
  const int wm = wid >> 2, wn = wid & 3;       // 2 x 4 wave grid
  const int l15 = lane & 15, l4 = lane >> 4;
  const int m0 = blockIdx.y * 256, n0 = blockIdx.x * 256;

  f32x4 acc[8][4];
  #pragma unroll
  for (int i=0;i<8;++i)
    #pragma unroll
    for (int j=0;j<4;++j) acc[i][j] = (f32x4)0.f;

  const int srow = t >> 3;          // base row for i=0 (rows advance by 64 per i)
  const int skq  = (t & 7) * 4;     // element offset within a 32-elem k-half

  for (int kp = 0; kp < K; kp += 64){
    // ---- stage A tile (256 rows x 64 k-elems fp32 -> bf16) ----
    #pragma unroll
    for (int i = 0; i < 4; ++i){
      int row = srow + i*64;
      const float* ap = A + (size_t)(m0+row)*K + kp + skq;
      uint2 w0 = pack_bf4(*(const float4*)ap);
      uint2 w1 = pack_bf4(*(const float4*)(ap + 32));
      int xr = (row & 7) << 4;
      *(uint2*)(As + row*128 + (( skq*2      ) ^ xr)) = w0;
      *(uint2*)(As + row*128 + ((64 + skq*2 ) ^ xr)) = w1;
    }
    // ---- stage B tile (bank rows, scaled by rn) ----
    #pragma unroll
    for (int i = 0; i < 4; ++i){
      int row = srow + i*64;
      int gn = n0 + row;
      float4 v0 = make_float4(0.f,0.f,0.f,0.f);
      float4 v1 = make_float4(0.f,0.f,0.f,0.f);
      float sc = 0.f;
      if (gn < Nn){
        const float* bp = Bm + (size_t)gn*K + kp + skq;
        v0 = *(const float4*)bp;
        v1 = *(const float4*)(bp + 32);
        sc = rn[gn];
      }
      v0.x*=sc; v0.y*=sc; v0.z*=sc; v0.w*=sc;
      v1.x*=sc; v1.y*=sc; v1.z*=sc; v1.w*=sc;
      uint2 w0 = pack_bf4(v0), w1 = pack_bf4(v1);
      int xr = (row & 7) << 4;
      *(uint2*)(Bs + row*128 + (( skq*2      ) ^ xr)) = w0;
      *(uint2*)(Bs + row*128 + ((64 + skq*2 ) ^ xr)) = w1;
    }
    __syncthreads();

    // ---- compute: 2 k-halves, 1 MFMA each per (fm,fn) ----
    bf16x8 B0[4], B1[4];
    #pragma unroll
    for (int fn = 0; fn < 4; ++fn){
      int brow = wn*64 + fn*16 + l15;
      int xr = (brow & 7) << 4;
      const unsigned char* bp = Bs + brow*128;
      B0[fn] = *(const bf16x8*)(bp + (( l4*16      ) ^ xr));
      B1[fn] = *(const bf16x8*)(bp + ((64 + l4*16 ) ^ xr));
    }
    #pragma unroll
    for (int fm = 0; fm < 8; ++fm){
      int arow = wm*128 + fm*16 + l15;
      int xr = (arow & 7) << 4;
      const unsigned char* ap = As + arow*128;
      bf16x8 A0 = *(const bf16x8*)(ap + (( l4*16      ) ^ xr));
      bf16x8 A1 = *(const bf16x8*)(ap + ((64 + l4*16 ) ^ xr));
      #pragma unroll
      for (int fn = 0; fn < 4; ++fn){
        acc[fm][fn] = __builtin_amdgcn_mfma_f32_16x16x32_bf16(A0, B0[fn], acc[fm][fn], 0,0,0);
        acc[fm][fn] = __builtin_amdgcn_mfma_f32_16x16x32_bf16(A1, B1[fn], acc[fm][fn], 0,0,0);
      }
    }
    __syncthreads();
  }

  // ---- store: C/D layout col=lane&15, row=(lane>>4)*4+reg ----
  #pragma unroll
  for (int fm = 0; fm < 8; ++fm){
    int row = m0 + wm*128 + fm*16 + l4*4;
    #pragma unroll
    for (int fn = 0; fn < 4; ++fn){
      int col = n0 + wn*64 + fn*16 + l15;
      if (col < Nn){
        float* cp = C + (size_t)row*ldc + col;
        #pragma unroll
        for (int r = 0; r < 4; ++r) cp[(size_t)r*ldc] = acc[fm][fn][r];
      }
    }
  }
}

// ---------- chunk filter: tau-threshold candidate selection ----------
__global__ __launch_bounds__(256) void chunk_filter_kernel(
    const float* __restrict__ scores, int ncols, int ldc,
    float* __restrict__ cand_s, int* __restrict__ cand_i,
    int col0, int chunk, int nchunks, int cap, float eps)
{
  __shared__ float sv[256];
  __shared__ float tau_s;
  __shared__ int cnt;
  const int row = blockIdx.x, t = threadIdx.x;
  const float* sr = scores + (size_t)row * ldc;

  float m = -INFINITY;
  for (int j = t; j < ncols; j += 256) m = fmaxf(m, sr[j]);
  sv[t] = m;
  __syncthreads();

  for (int k = 2; k <= 256; k <<= 1){
    for (int j = k >> 1; j > 0; j >>= 1){
      int p = t ^ j;
      float a = sv[t], b = sv[p];
      bool up = ((t & k) == 0);
      float keep = (t < p) ? (up ? fmaxf(a,b) : fminf(a,b))
                           : (up ? fminf(a,b) : fmaxf(a,b));
      __syncthreads();
      sv[t] = keep;
      __syncthreads();
    }
  }
  if (t == 0){ tau_s = sv[31]; cnt = 0; }
  __syncthreads();
  const float thr = tau_s - eps;

  float* cs = cand_s + ((size_t)row * nchunks + chunk) * cap;
  int*   ci = cand_i + ((size_t)row * nchunks + chunk) * cap;

  for (int j = t; j < ncols; j += 256){
    float v = sr[j];
    if (v >= thr){
      int pos = atomicAdd(&cnt, 1);
      if (pos < cap){ cs[pos] = v; ci[pos] = col0 + j; }
    }
  }
  __syncthreads();
  int n = cnt < cap ? cnt : cap;
  for (int j = n + t; j < cap; j += 256) ci[j] = -1;
}

// ---------- select: prune (tau-trick on approx) -> fp32 rescore -> sort ----------
__global__ __launch_bounds__(256) void select_softmax_gather_kernel(
    const float* __restrict__ cand_s, const int* __restrict__ cand_i,
    const float* __restrict__ p, const float* __restrict__ rn_bank,
    const float* __restrict__ pnorm, const float* __restrict__ bank,
    float* __restrict__ z, int ncap, int D, int topm, float invtemp, float eps)
{
  __shared__ float p_s[1024];
  __shared__ float vs[1024]; __shared__ int vi[1024];
  __shared__ float sv[256];
  __shared__ int   cidx[256];
  __shared__ float rv[256];
  __shared__ float tau_s;
  __shared__ int cnt;
  const int row = blockIdx.x, t = threadIdx.x;
  const int lane = t & 63, wid = t >> 6;

  const float4* pr = (const float4*)(p + (size_t)row * D);
  for (int i = t; i < (D >> 2); i += 256) ((float4*)p_s)[i] = pr[i];
  const float* cs = cand_s + (size_t)row * ncap;
  const int*  ci = cand_i + (size_t)row * ncap;
  for (int j = t; j < ncap; j += 256){
    int k = ci[j];
    vi[j] = k;
    vs[j] = (k >= 0) ? cs[j] : -INFINITY;
  }
  __syncthreads();

  float m = -INFINITY;
  for (int j = t; j < ncap; j += 256) m = fmaxf(m, vs[j]);
  sv[t] = m;
  __syncthreads();
  for (int k = 2; k <= 256; k <<= 1){
    for (int j = k >> 1; j > 0; j >>= 1){
      int pp = t ^ j;
      float a = sv[t], b = sv[pp];
      bool up = ((t & k) == 0);
      float keep = (t < pp) ? (up ? fmaxf(a,b) : fminf(a,b))
                            : (up ? fminf(a,b) : fmaxf(a,b));
      __syncthreads();
      sv[t] = keep;
      __syncthreads();
    }
  }
  if (t == 0){ tau_s = sv[31]; cnt = 0; }
  __syncthreads();
  const float thr = tau_s - eps;

  for (int j = t; j < ncap; j += 256){
    if (vi[j] >= 0 && vs[j] >= thr){
      int pos = atomicAdd(&cnt, 1);
      if (pos < 256) cidx[pos] = vi[j];
    }
  }
  __syncthreads();
  const int n2 = cnt < 256 ? cnt : 256;
  rv[t] = -INFINITY;
  if (t >= n2) cidx[t] = 0x7fffffff;
  __syncthreads();

  const int nj = D >> 8;
  for (int c = wid; c < n2; c += 4){
    int idx = cidx[c];
    const float4* kr = (const float4*)(bank + (size_t)idx * D);
    float ss = 0.f;
    for (int j = 0; j < nj; ++j){
      float4 kv = kr[lane + j*64];
      float4 pv = *(const float4*)&p_s[(lane + j*64) << 2];
      ss = fmaf(pv.x,kv.x, fmaf(pv.y,kv.y, fmaf(pv.z,kv.z, fmaf(pv.w,kv.w, ss))));
    }
    #pragma unroll
    for (int off = 32; off; off >>= 1) ss += __shfl_xor(ss, off);
    if (lane == 0) rv[c] = ss * rn_bank[idx];
  }
  __syncthreads();

  for (int k = 2; k <= 256; k <<= 1){
    for (int j = k >> 1; j > 0; j >>= 1){
      int pp = t ^ j;
      float av = rv[t];  int ai = cidx[t];
      float bv = rv[pp]; int bi = cidx[pp];
      bool up = ((t & k) == 0);
      bool agtb = (av > bv) || (av == bv && ai < bi);
      bool keepA = (t < pp) ? (up ? agtb : !agtb)
                            : (up ? !agtb : agtb);
      __syncthreads();
      if (keepA){ rv[t] = av; cidx[t] = ai; } else { rv[t] = bv; cidx[t] = bi; }
      __syncthreads();
    }
  }

  if (t == 0){
    float pn = pnorm[row] * invtemp;
    float mx = rv[0] * pn;
    float sum = 0.f;
    for (int i = 0; i < topm; ++i){
      float w = expf(rv[i]*pn - mx);
      sv[i] = w; sum += w;
    }
    float inv = 1.f / sum;
    for (int i = 0; i < topm; ++i) sv[i] *= inv;
  }
  __syncthreads();

  for (int d4 = t; d4 < (D >> 2); d4 += 256){
    float ax=0.f, ay=0.f, az=0.f, aw=0.f;
    for (int i = 0; i < topm; ++i){
      float a = sv[i];
      const float4 v = *(const float4*)(bank + (size_t)cidx[i]*D + (d4<<2));
      ax = fmaf(a, v.x, ax); ay = fmaf(a, v.y, ay);
      az = fmaf(a, v.z, az); aw = fmaf(a, v.w, aw);
    }
    *(float4*)(z + (size_t)row*D + (d4<<2)) = make_float4(ax,ay,az,aw);
  }
}

// ---------- LayerNorm ----------
__global__ __launch_bounds__(256) void layernorm_kernel(
    const float* __restrict__ ref, const float* __restrict__ gamma,
    const float* __restrict__ beta, float* __restrict__ out, int D, float eps)
{
  __shared__ float s1[4], s2[4];
  const int row = blockIdx.x, t = threadIdx.x;
  const float4* xr = (const float4*)(ref + (size_t)row*D);
  int nv = D >> 2;
  float sum = 0.f, ssq = 0.f;
  for (int i = t; i < nv; i += 256){
    float4 v = xr[i];
    sum += v.x+v.y+v.z+v.w;
    ssq = fmaf(v.x,v.x, fmaf(v.y,v.y, fmaf(v.z,v.z, fmaf(v.w,v.w, ssq))));
  }
  const int lane = t & 63, wid = t >> 6;
  #pragma unroll
  for (int off = 32; off; off >>= 1){ sum += __shfl_xor(sum, off); ssq += __shfl_xor(ssq, off); }
  if (lane == 0){ s1[wid] = sum; s2[wid] = ssq; }
  __syncthreads();
  sum = s1[0]+s1[1]+s1[2]+s1[3];
  ssq = s2[0]+s2[1]+s2[2]+s2[3];
  float mu  = sum / (float)D;
  float var = ssq / (float)D - mu*mu;
  float rs  = rsqrtf(var + eps);
  const float4* g4 = (const float4*)gamma;
  const float4* b4 = (const float4*)beta;
  float4* o4 = (float4*)(out + (size_t)row*D);
  for (int i = t; i < nv; i += 256){
    float4 v = xr[i], g = g4[i], bb = b4[i];
    float4 o;
    o.x = (v.x-mu)*rs*g.x + bb.x;
    o.y = (v.y-mu)*rs*g.y + bb.y;
    o.z = (v.z-mu)*rs*g.z + bb.z;
    o.w = (v.w-mu)*rs*g.w + bb.w;
    o4[i] = o;
  }
}

// ---------------------------------------------------------------------------
extern "C" void kernel_launch(void* const* d_in, const int* in_sizes, int n_in,
                              void* d_out, int out_size, void* d_ws, size_t ws_size,
                              hipStream_t stream)
{
  const float* q       = (const float*)d_in[0];
  const float* bank    = (const float*)d_in[1];
  const float* proj_w  = (const float*)d_in[2];
  const float* proj_b  = (const float*)d_in[3];
  const float* unify_w = (const float*)d_in[4];
  const float* unify_b = (const float*)d_in[5];
  const float* gamma   = (const float*)d_in[6];
  const float* beta    = (const float*)d_in[7];

  const int D = in_sizes[6];
  const int B = in_sizes[0] / D;
  const int N = in_sizes[1] / D;
  const int S = in_sizes[2] / (D * D);
  const int TOPM = 32;
  const int CAP  = 64;               // candidate slots per (row,chunk)
  const float INVTEMP = 1.0f / 0.07f;
  const float EPS = 0.025f;          // >= 2x max bf16 score error (~7e-3)

  // --- workspace sizing (adaptive; ncap must stay <= 1024 for select LDS) ---
  size_t fixed = align256((size_t)N*4) + align256((size_t)B*4) + 3*align256((size_t)B*D*4);
  const int ncopts[3] = {12544, 8192, 6272};
  int NC = 6272;
  for (int ci = 0; ci < 3; ++ci){
    int cand = ncopts[ci];
    int nch = (N + cand - 1) / cand;
    size_t tot = fixed + align256((size_t)B*cand*4) + 2*align256((size_t)B*nch*CAP*4);
    if (tot <= ws_size){ NC = cand; break; }
  }
  const int NCH = (N + NC - 1) / NC;

  char* wsb = (char*)d_ws;
  size_t off = 0;
  auto take = [&](size_t bytes)->char*{ char* p = wsb + off; off += align256(bytes); return p; };
  float* rn_bank = (float*)take((size_t)N*4);
  float* pnorm   = (float*)take((size_t)B*4);
  float* p       = (float*)take((size_t)B*D*4);
  float* z       = (float*)take((size_t)B*D*4);
  float* ref     = (float*)take((size_t)B*D*4);
  float* scores  = (float*)take((size_t)B*NC*4);
  float* cand_s  = (float*)take((size_t)B*NCH*CAP*4);
  int*   cand_i  = (int*)  take((size_t)B*NCH*CAP*4);

  // 1) bank key inverse norms
  row_rnorm_kernel<<<(N+3)/4, 256, 0, stream>>>(bank, rn_bank, N, D);

  for (int s = 0; s < S; ++s){
    // 2) p = q @ proj_w[s]^T + proj_b[s]
    dim3 g1(D/64, B/64);
    gemm_nt_kernel<1,1,false><<<g1, 256, 0, stream>>>(
        q, proj_w + (size_t)s*D*D, proj_b + (size_t)s*D, nullptr,
        p, B, D, D, D, D);
    // 3) ||p|| row norms
    row_rnorm_kernel<<<(B+3)/4, 256, 0, stream>>>(p, pnorm, B, D);

    // 4) chunked approx scores (bf16 MFMA, BK=64) + tau-filter candidates
    for (int c = 0; c < NCH; ++c){
      int n0 = c * NC;
      int nv = N - n0; if (nv > NC) nv = NC;
      dim3 g2((nv + 255)/256, B/256);
      scores_mfma_kernel<<<g2, 512, 0, stream>>>(
          p, bank + (size_t)n0*D, rn_bank + n0,
          scores, B, nv, D, NC);
      chunk_filter_kernel<<<B, 256, 0, stream>>>(
          scores, nv, NC, cand_s, cand_i, n0, c, NCH, CAP, EPS);
    }

    // 5) prune + fp32 rescore + exact top-32 + softmax + gather
    select_softmax_gather_kernel<<<B, 256, 0, stream>>>(
        cand_s, cand_i, p, rn_bank, pnorm, bank, z,
        NCH*CAP, D, TOPM, INVTEMP, EPS);

    // 6) ref (+)= z @ unify_w[s]^T + unify_b[s]
    if (s == 0)
      gemm_nt_kernel<1,1,false><<<g1, 256, 0, stream>>>(
          z, unify_w + (size_t)s*D*D, unify_b + (size_t)s*D, nullptr,
          ref, B, D, D, D, D);
    else
      gemm_nt_kernel<1,1,true><<<g1, 256, 0, stream>>>(
          z, unify_w + (size_t)s*D*D, unify_b + (size_t)s*D, nullptr,
          ref, B, D, D, D, D);
  }

  // 7) LayerNorm -> out
  layernorm_kernel<<<B, 256, 0, stream>>>(ref, gamma, beta, (float*)d_out, D, 1e-5f);
}

// Round 9
// 2099.484 us; speedup vs baseline: 5.8807x; 1.1120x over previous
//
#include <hip/hip_runtime.h>
#include <math.h>

// ---------------------------------------------------------------------------
// MultiScaleRetriever round 9: (a) filter de-latency'd: float4 + 4-way ILP max
// + LDS-cached chunk (pass 2 reads LDS); (b) scores as ONE full-N dispatch per
// scale (1564 blocks, full residency) + one (B x NCH) filter dispatch.
// Scores kernel inner loop byte-identical to passing R8.
// ---------------------------------------------------------------------------

static inline size_t align256(size_t x){ return (x + 255) & ~size_t(255); }

typedef short bf16x8 __attribute__((ext_vector_type(8)));
typedef float f32x4  __attribute__((ext_vector_type(4)));

__device__ inline unsigned short f2bf(float f){
  unsigned int u = __float_as_uint(f);
  u += 0x7fffu + ((u >> 16) & 1u);
  return (unsigned short)(u >> 16);
}
__device__ inline uint2 pack_bf4(float4 v){
  uint2 w;
  w.x = (unsigned)f2bf(v.x) | ((unsigned)f2bf(v.y) << 16);
  w.y = (unsigned)f2bf(v.z) | ((unsigned)f2bf(v.w) << 16);
  return w;
}

// ---------- per-row 1/max(||x||,1e-12) ----------
__global__ __launch_bounds__(256) void row_rnorm_kernel(
    const float* __restrict__ X, float* __restrict__ rn, int rows, int D)
{
  int wv = threadIdx.x >> 6, lane = threadIdx.x & 63;
  int r = blockIdx.x * 4 + wv;
  if (r >= rows) return;
  const float4* xr = (const float4*)(X + (size_t)r * D);
  int nv = D >> 2;
  float ss = 0.f;
  for (int i = lane; i < nv; i += 64){
    float4 v = xr[i];
    ss = fmaf(v.x,v.x, fmaf(v.y,v.y, fmaf(v.z,v.z, fmaf(v.w,v.w, ss))));
  }
  #pragma unroll
  for (int off = 32; off; off >>= 1) ss += __shfl_xor(ss, off);
  if (lane == 0) rn[r] = 1.f / fmaxf(sqrtf(ss), 1e-12f);
}

// ---------- fp32 NT GEMM (proj/unify) ----------
template<int RM, int RN, bool ACCUM>
__global__ __launch_bounds__(256) void gemm_nt_kernel(
    const float* __restrict__ A, const float* __restrict__ B,
    const float* __restrict__ bias, const float* __restrict__ bscale,
    float* __restrict__ C, int M, int Nn, int K, int Brows, int ldc)
{
  __shared__ float As[16][RM*64 + 4];
  __shared__ float Bs[16][RN*64 + 4];
  const int t  = threadIdx.x;
  const int tm = t >> 4, tn = t & 15;
  const int m0 = blockIdx.y * (RM*64), n0 = blockIdx.x * (RN*64);

  float acc[RM][RN][4][4];
  #pragma unroll
  for (int r=0;r<RM;++r)
    #pragma unroll
    for (int c=0;c<RN;++c)
      #pragma unroll
      for (int i=0;i<4;++i)
        #pragma unroll
        for (int j=0;j<4;++j) acc[r][c][i][j]=0.f;

  for (int kp = 0; kp < K; kp += 16){
    #pragma unroll
    for (int l = 0; l < RM; ++l){
      int li = t + l*256;
      int row = li >> 2, kq = (li & 3) << 2;
      float4 v = *(const float4*)(A + (size_t)(m0+row)*K + kp + kq);
      As[kq+0][row]=v.x; As[kq+1][row]=v.y; As[kq+2][row]=v.z; As[kq+3][row]=v.w;
    }
    #pragma unroll
    for (int l = 0; l < RN; ++l){
      int li = t + l*256;
      int row = li >> 2, kq = (li & 3) << 2;
      int gn = n0 + row;
      float4 v = make_float4(0.f,0.f,0.f,0.f);
      float sc = 1.f;
      if (gn < Brows){
        v = *(const float4*)(B + (size_t)gn*K + kp + kq);
        if (bscale) sc = bscale[gn];
      }
      Bs[kq+0][row]=v.x*sc; Bs[kq+1][row]=v.y*sc; Bs[kq+2][row]=v.z*sc; Bs[kq+3][row]=v.w*sc;
    }
    __syncthreads();
    #pragma unroll
    for (int kk = 0; kk < 16; ++kk){
      float av[RM][4], bv[RN][4];
      #pragma unroll
      for (int r=0;r<RM;++r){
        float4 a = *(const float4*)&As[kk][r*64 + tm*4];
        av[r][0]=a.x; av[r][1]=a.y; av[r][2]=a.z; av[r][3]=a.w;
      }
      #pragma unroll
      for (int c=0;c<RN;++c){
        float4 b = *(const float4*)&Bs[kk][c*64 + tn*4];
        bv[c][0]=b.x; bv[c][1]=b.y; bv[c][2]=b.z; bv[c][3]=b.w;
      }
      #pragma unroll
      for (int r=0;r<RM;++r)
        #pragma unroll
        for (int c=0;c<RN;++c)
          #pragma unroll
          for (int i=0;i<4;++i)
            #pragma unroll
            for (int j=0;j<4;++j)
              acc[r][c][i][j] = fmaf(av[r][i], bv[c][j], acc[r][c][i][j]);
    }
    __syncthreads();
  }

  #pragma unroll
  for (int r=0;r<RM;++r){
    #pragma unroll
    for (int i=0;i<4;++i){
      int gm = m0 + r*64 + tm*4 + i;
      #pragma unroll
      for (int c=0;c<RN;++c){
        int gn = n0 + c*64 + tn*4;
        if (gn >= Nn) continue;
        float* cp = C + (size_t)gm*ldc + gn;
        float o0=acc[r][c][i][0], o1=acc[r][c][i][1], o2=acc[r][c][i][2], o3=acc[r][c][i][3];
        if (gn + 3 < Nn){
          float4 o = make_float4(o0,o1,o2,o3);
          if (bias){ float4 bb = *(const float4*)&bias[gn]; o.x+=bb.x; o.y+=bb.y; o.z+=bb.z; o.w+=bb.w; }
          if (ACCUM){ float4 cc = *(const float4*)cp; o.x+=cc.x; o.y+=cc.y; o.z+=cc.z; o.w+=cc.w; }
          *(float4*)cp = o;
        } else {
          float ov[4] = {o0,o1,o2,o3};
          for (int j=0;j<4;++j){
            if (gn + j < Nn){
              float o = ov[j];
              if (bias)  o += bias[gn+j];
              if (ACCUM) o += cp[j];
              cp[j] = o;
            }
          }
        }
      }
    }
  }
}

// ---------- scores GEMM: plain bf16 MFMA, BK=64, 256x256 tile, 8 waves ----------
// (inner loop identical to passing R8; now launched once per scale over full N)
__global__ __launch_bounds__(512, 2) void scores_mfma_kernel(
    const float* __restrict__ A, const float* __restrict__ Bm,
    const float* __restrict__ rn, float* __restrict__ C,
    int M, int Nn, int K, int ldc)
{
  __shared__ __align__(16) unsigned char smem[65536];   // A: [0,32K), B: [32K,64K)
  unsigned char* As = smem;
  unsigned char* Bs = smem + 32768;

  const int t = threadIdx.x;
  const int lane = t & 63, wid = t >> 6;
  const int wm = wid >> 2, wn = wid & 3;       // 2 x 4 wave grid
  const int l15 = lane & 15, l4 = lane >> 4;
  const int m0 = blockIdx.y * 256, n0 = blockIdx.x * 256;

  f32x4 acc[8][4];
  #pragma unroll
  for (int i=0;i<8;++i)
    #pragma unroll
    for (int j=0;j<4;++j) acc[i][j] = (f32x4)0.f;

  const int srow = t >> 3;
  const int skq  = (t & 7) * 4;

  for (int kp = 0; kp < K; kp += 64){
    #pragma unroll
    for (int i = 0; i < 4; ++i){
      int row = srow + i*64;
      const float* ap = A + (size_t)(m0+row)*K + kp + skq;
      uint2 w0 = pack_bf4(*(const float4*)ap);
      uint2 w1 = pack_bf4(*(const float4*)(ap + 32));
      int xr = (row & 7) << 4;
      *(uint2*)(As + row*128 + (( skq*2      ) ^ xr)) = w0;
      *(uint2*)(As + row*128 + ((64 + skq*2 ) ^ xr)) = w1;
    }
    #pragma unroll
    for (int i = 0; i < 4; ++i){
      int row = srow + i*64;
      int gn = n0 + row;
      float4 v0 = make_float4(0.f,0.f,0.f,0.f);
      float4 v1 = make_float4(0.f,0.f,0.f,0.f);
      float sc = 0.f;
      if (gn < Nn){
        const float* bp = Bm + (size_t)gn*K + kp + skq;
        v0 = *(const float4*)bp;
        v1 = *(const float4*)(bp + 32);
        sc = rn[gn];
      }
      v0.x*=sc; v0.y*=sc; v0.z*=sc; v0.w*=sc;
      v1.x*=sc; v1.y*=sc; v1.z*=sc; v1.w*=sc;
      uint2 w0 = pack_bf4(v0), w1 = pack_bf4(v1);
      int xr = (row & 7) << 4;
      *(uint2*)(Bs + row*128 + (( skq*2      ) ^ xr)) = w0;
      *(uint2*)(Bs + row*128 + ((64 + skq*2 ) ^ xr)) = w1;
    }
    __syncthreads();

    bf16x8 B0[4], B1[4];
    #pragma unroll
    for (int fn = 0; fn < 4; ++fn){
      int brow = wn*64 + fn*16 + l15;
      int xr = (brow & 7) << 4;
      const unsigned char* bp = Bs + brow*128;
      B0[fn] = *(const bf16x8*)(bp + (( l4*16      ) ^ xr));
      B1[fn] = *(const bf16x8*)(bp + ((64 + l4*16 ) ^ xr));
    }
    #pragma unroll
    for (int fm = 0; fm < 8; ++fm){
      int arow = wm*128 + fm*16 + l15;
      int xr = (arow & 7) << 4;
      const unsigned char* ap = As + arow*128;
      bf16x8 A0 = *(const bf16x8*)(ap + (( l4*16      ) ^ xr));
      bf16x8 A1 = *(const bf16x8*)(ap + ((64 + l4*16 ) ^ xr));
      #pragma unroll
      for (int fn = 0; fn < 4; ++fn){
        acc[fm][fn] = __builtin_amdgcn_mfma_f32_16x16x32_bf16(A0, B0[fn], acc[fm][fn], 0,0,0);
        acc[fm][fn] = __builtin_amdgcn_mfma_f32_16x16x32_bf16(A1, B1[fn], acc[fm][fn], 0,0,0);
      }
    }
    __syncthreads();
  }

  #pragma unroll
  for (int fm = 0; fm < 8; ++fm){
    int row = m0 + wm*128 + fm*16 + l4*4;
    #pragma unroll
    for (int fn = 0; fn < 4; ++fn){
      int col = n0 + wn*64 + fn*16 + l15;
      if (col < Nn){
        float* cp = C + (size_t)row*ldc + col;
        #pragma unroll
        for (int r = 0; r < 4; ++r) cp[(size_t)r*ldc] = acc[fm][fn][r];
      }
    }
  }
}

// ---------- chunk filter v2: float4 + 4-way ILP max, LDS-cached chunk ----------
// grid = (B, nchunks_in_window). tau = 32nd of 256 per-thread maxima
// (partition = float4-strided; any 256-cover partition preserves the
// superset guarantee). Pass 2 reads the LDS copy, not global.
__global__ __launch_bounds__(256) void chunk_filter_kernel(
    const float* __restrict__ scores, int ldc, int colbase, int Nwindow,
    int NC, float* __restrict__ cand_s, int* __restrict__ cand_i,
    int chunk0, int nchunks_total, int cap, float eps)
{
  extern __shared__ float lds[];          // NC floats
  __shared__ float sv[256];
  __shared__ float tau_s;
  __shared__ int cnt;
  const int row = blockIdx.x, t = threadIdx.x;
  const int lc = blockIdx.y;
  const int col0l = lc * NC;
  int ncols = Nwindow - col0l; if (ncols > NC) ncols = NC;
  const int gchunk = chunk0 + lc;
  const float* sr = scores + (size_t)row * ldc + col0l;

  // pass 1: copy to LDS + 4-way ILP per-thread max
  float m0 = -INFINITY, m1 = -INFINITY, m2 = -INFINITY, m3 = -INFINITY;
  const int nc4 = ncols >> 2;
  const float4* sr4 = (const float4*)sr;
  float4* lds4 = (float4*)lds;
  for (int j = t; j < nc4; j += 256){
    float4 v = sr4[j];
    lds4[j] = v;
    m0 = fmaxf(m0, v.x); m1 = fmaxf(m1, v.y);
    m2 = fmaxf(m2, v.z); m3 = fmaxf(m3, v.w);
  }
  for (int j = (nc4 << 2) + t; j < ncols; j += 256){
    float v = sr[j];
    lds[j] = v;
    m0 = fmaxf(m0, v);
  }
  sv[t] = fmaxf(fmaxf(m0, m1), fmaxf(m2, m3));
  __syncthreads();

  // bitonic sort 256 descending; tau = sv[31]
  for (int k = 2; k <= 256; k <<= 1){
    for (int j = k >> 1; j > 0; j >>= 1){
      int p = t ^ j;
      float a = sv[t], b = sv[p];
      bool up = ((t & k) == 0);
      float keep = (t < p) ? (up ? fmaxf(a,b) : fminf(a,b))
                           : (up ? fminf(a,b) : fmaxf(a,b));
      __syncthreads();
      sv[t] = keep;
      __syncthreads();
    }
  }
  if (t == 0){ tau_s = sv[31]; cnt = 0; }
  __syncthreads();
  const float thr = tau_s - eps;

  float* cs = cand_s + ((size_t)row * nchunks_total + gchunk) * cap;
  int*   ci = cand_i + ((size_t)row * nchunks_total + gchunk) * cap;

  // pass 2: compact from LDS
  for (int j = t; j < ncols; j += 256){
    float v = lds[j];
    if (v >= thr){
      int pos = atomicAdd(&cnt, 1);
      if (pos < cap){ cs[pos] = v; ci[pos] = colbase + col0l + j; }
    }
  }
  __syncthreads();
  int n = cnt < cap ? cnt : cap;
  for (int j = n + t; j < cap; j += 256) ci[j] = -1;
}

// ---------- select: prune (tau-trick on approx) -> fp32 rescore -> sort ----------
__global__ __launch_bounds__(256) void select_softmax_gather_kernel(
    const float* __restrict__ cand_s, const int* __restrict__ cand_i,
    const float* __restrict__ p, const float* __restrict__ rn_bank,
    const float* __restrict__ pnorm, const float* __restrict__ bank,
    float* __restrict__ z, int ncap, int D, int topm, float invtemp, float eps)
{
  __shared__ float p_s[1024];
  __shared__ float vs[1024]; __shared__ int vi[1024];
  __shared__ float sv[256];
  __shared__ int   cidx[256];
  __shared__ float rv[256];
  __shared__ float tau_s;
  __shared__ int cnt;
  const int row = blockIdx.x, t = threadIdx.x;
  const int lane = t & 63, wid = t >> 6;

  const float4* pr = (const float4*)(p + (size_t)row * D);
  for (int i = t; i < (D >> 2); i += 256) ((float4*)p_s)[i] = pr[i];
  const float* cs = cand_s + (size_t)row * ncap;
  const int*  ci = cand_i + (size_t)row * ncap;
  for (int j = t; j < ncap; j += 256){
    int k = ci[j];
    vi[j] = k;
    vs[j] = (k >= 0) ? cs[j] : -INFINITY;
  }
  __syncthreads();

  float m = -INFINITY;
  for (int j = t; j < ncap; j += 256) m = fmaxf(m, vs[j]);
  sv[t] = m;
  __syncthreads();
  for (int k = 2; k <= 256; k <<= 1){
    for (int j = k >> 1; j > 0; j >>= 1){
      int pp = t ^ j;
      float a = sv[t], b = sv[pp];
      bool up = ((t & k) == 0);
      float keep = (t < pp) ? (up ? fmaxf(a,b) : fminf(a,b))
                            : (up ? fminf(a,b) : fmaxf(a,b));
      __syncthreads();
      sv[t] = keep;
      __syncthreads();
    }
  }
  if (t == 0){ tau_s = sv[31]; cnt = 0; }
  __syncthreads();
  const float thr = tau_s - eps;

  for (int j = t; j < ncap; j += 256){
    if (vi[j] >= 0 && vs[j] >= thr){
      int pos = atomicAdd(&cnt, 1);
      if (pos < 256) cidx[pos] = vi[j];
    }
  }
  __syncthreads();
  const int n2 = cnt < 256 ? cnt : 256;
  rv[t] = -INFINITY;
  if (t >= n2) cidx[t] = 0x7fffffff;
  __syncthreads();

  const int nj = D >> 8;
  for (int c = wid; c < n2; c += 4){
    int idx = cidx[c];
    const float4* kr = (const float4*)(bank + (size_t)idx * D);
    float ss = 0.f;
    for (int j = 0; j < nj; ++j){
      float4 kv = kr[lane + j*64];
      float4 pv = *(const float4*)&p_s[(lane + j*64) << 2];
      ss = fmaf(pv.x,kv.x, fmaf(pv.y,kv.y, fmaf(pv.z,kv.z, fmaf(pv.w,kv.w, ss))));
    }
    #pragma unroll
    for (int off = 32; off; off >>= 1) ss += __shfl_xor(ss, off);
    if (lane == 0) rv[c] = ss * rn_bank[idx];
  }
  __syncthreads();

  for (int k = 2; k <= 256; k <<= 1){
    for (int j = k >> 1; j > 0; j >>= 1){
      int pp = t ^ j;
      float av = rv[t];  int ai = cidx[t];
      float bv = rv[pp]; int bi = cidx[pp];
      bool up = ((t & k) == 0);
      bool agtb = (av > bv) || (av == bv && ai < bi);
      bool keepA = (t < pp) ? (up ? agtb : !agtb)
                            : (up ? !agtb : agtb);
      __syncthreads();
      if (keepA){ rv[t] = av; cidx[t] = ai; } else { rv[t] = bv; cidx[t] = bi; }
      __syncthreads();
    }
  }

  if (t == 0){
    float pn = pnorm[row] * invtemp;
    float mx = rv[0] * pn;
    float sum = 0.f;
    for (int i = 0; i < topm; ++i){
      float w = expf(rv[i]*pn - mx);
      sv[i] = w; sum += w;
    }
    float inv = 1.f / sum;
    for (int i = 0; i < topm; ++i) sv[i] *= inv;
  }
  __syncthreads();

  for (int d4 = t; d4 < (D >> 2); d4 += 256){
    float ax=0.f, ay=0.f, az=0.f, aw=0.f;
    for (int i = 0; i < topm; ++i){
      float a = sv[i];
      const float4 v = *(const float4*)(bank + (size_t)cidx[i]*D + (d4<<2));
      ax = fmaf(a, v.x, ax); ay = fmaf(a, v.y, ay);
      az = fmaf(a, v.z, az); aw = fmaf(a, v.w, aw);
    }
    *(float4*)(z + (size_t)row*D + (d4<<2)) = make_float4(ax,ay,az,aw);
  }
}

// ---------- LayerNorm ----------
__global__ __launch_bounds__(256) void layernorm_kernel(
    const float* __restrict__ ref, const float* __restrict__ gamma,
    const float* __restrict__ beta, float* __restrict__ out, int D, float eps)
{
  __shared__ float s1[4], s2[4];
  const int row = blockIdx.x, t = threadIdx.x;
  const float4* xr = (const float4*)(ref + (size_t)row*D);
  int nv = D >> 2;
  float sum = 0.f, ssq = 0.f;
  for (int i = t; i < nv; i += 256){
    float4 v = xr[i];
    sum += v.x+v.y+v.z+v.w;
    ssq = fmaf(v.x,v.x, fmaf(v.y,v.y, fmaf(v.z,v.z, fmaf(v.w,v.w, ssq))));
  }
  const int lane = t & 63, wid = t >> 6;
  #pragma unroll
  for (int off = 32; off; off >>= 1){ sum += __shfl_xor(sum, off); ssq += __shfl_xor(ssq, off); }
  if (lane == 0){ s1[wid] = sum; s2[wid] = ssq; }
  __syncthreads();
  sum = s1[0]+s1[1]+s1[2]+s1[3];
  ssq = s2[0]+s2[1]+s2[2]+s2[3];
  float mu  = sum / (float)D;
  float var = ssq / (float)D - mu*mu;
  float rs  = rsqrtf(var + eps);
  const float4* g4 = (const float4*)gamma;
  const float4* b4 = (const float4*)beta;
  float4* o4 = (float4*)(out + (size_t)row*D);
  for (int i = t; i < nv; i += 256){
    float4 v = xr[i], g = g4[i], bb = b4[i];
    float4 o;
    o.x = (v.x-mu)*rs*g.x + bb.x;
    o.y = (v.y-mu)*rs*g.y + bb.y;
    o.z = (v.z-mu)*rs*g.z + bb.z;
    o.w = (v.w-mu)*rs*g.w + bb.w;
    o4[i] = o;
  }
}

// ---------------------------------------------------------------------------
extern "C" void kernel_launch(void* const* d_in, const int* in_sizes, int n_in,
                              void* d_out, int out_size, void* d_ws, size_t ws_size,
                              hipStream_t stream)
{
  const float* q       = (const float*)d_in[0];
  const float* bank    = (const float*)d_in[1];
  const float* proj_w  = (const float*)d_in[2];
  const float* proj_b  = (const float*)d_in[3];
  const float* unify_w = (const float*)d_in[4];
  const float* unify_b = (const float*)d_in[5];
  const float* gamma   = (const float*)d_in[6];
  const float* beta    = (const float*)d_in[7];

  const int D = in_sizes[6];
  const int B = in_sizes[0] / D;
  const int N = in_sizes[1] / D;
  const int S = in_sizes[2] / (D * D);
  const int TOPM = 32;
  const int CAP  = 64;
  const int NC   = 12544;            // filter chunk width (50KB LDS cache)
  const float INVTEMP = 1.0f / 0.07f;
  const float EPS = 0.025f;          // >= 2x max bf16 score error (~7e-3)

  const int NCH = (N + NC - 1) / NC;

  // --- workspace: prefer full-N scores window; fall back to NC-wide windows ---
  size_t fixed = align256((size_t)N*4) + align256((size_t)B*4) + 3*align256((size_t)B*D*4)
               + 2*align256((size_t)B*NCH*CAP*4);
  int SCN = N;                                            // scores window width
  if (fixed + align256((size_t)B*(size_t)N*4) > ws_size) SCN = NC;

  char* wsb = (char*)d_ws;
  size_t off = 0;
  auto take = [&](size_t bytes)->char*{ char* p = wsb + off; off += align256(bytes); return p; };
  float* rn_bank = (float*)take((size_t)N*4);
  float* pnorm   = (float*)take((size_t)B*4);
  float* p       = (float*)take((size_t)B*D*4);
  float* z       = (float*)take((size_t)B*D*4);
  float* ref     = (float*)take((size_t)B*D*4);
  float* cand_s  = (float*)take((size_t)B*NCH*CAP*4);
  int*   cand_i  = (int*)  take((size_t)B*NCH*CAP*4);
  float* scores  = (float*)take((size_t)B*(size_t)SCN*4);

  // 1) bank key inverse norms
  row_rnorm_kernel<<<(N+3)/4, 256, 0, stream>>>(bank, rn_bank, N, D);

  for (int s = 0; s < S; ++s){
    // 2) p = q @ proj_w[s]^T + proj_b[s]
    dim3 g1(D/64, B/64);
    gemm_nt_kernel<1,1,false><<<g1, 256, 0, stream>>>(
        q, proj_w + (size_t)s*D*D, proj_b + (size_t)s*D, nullptr,
        p, B, D, D, D, D);
    // 3) ||p|| row norms
    row_rnorm_kernel<<<(B+3)/4, 256, 0, stream>>>(p, pnorm, B, D);

    // 4) scores (bf16 MFMA, window = full N when ws allows) + tau-filter
    for (int w0 = 0; w0 < N; w0 += SCN){
      int nw = N - w0; if (nw > SCN) nw = SCN;
      dim3 g2((nw + 255)/256, B/256);
      scores_mfma_kernel<<<g2, 512, 0, stream>>>(
          p, bank + (size_t)w0*D, rn_bank + w0,
          scores, B, nw, D, SCN);
      int ncw = (nw + NC - 1) / NC;
      chunk_filter_kernel<<<dim3(B, ncw), 256, (size_t)NC*4, stream>>>(
          scores, SCN, w0, nw, NC, cand_s, cand_i,
          w0 / NC, NCH, CAP, EPS);
    }

    // 5) prune + fp32 rescore + exact top-32 + softmax + gather
    select_softmax_gather_kernel<<<B, 256, 0, stream>>>(
        cand_s, cand_i, p, rn_bank, pnorm, bank, z,
        NCH*CAP, D, TOPM, INVTEMP, EPS);

    // 6) ref (+)= z @ unify_w[s]^T + unify_b[s]
    if (s == 0)
      gemm_nt_kernel<1,1,false><<<g1, 256, 0, stream>>>(
          z, unify_w + (size_t)s*D*D, unify_b + (size_t)s*D, nullptr,
          ref, B, D, D, D, D);
    else
      gemm_nt_kernel<1,1,true><<<g1, 256, 0, stream>>>(
          z, unify_w + (size_t)s*D*D, unify_b + (size_t)s*D, nullptr,
          ref, B, D, D, D, D);
  }

  // 7) LayerNorm -> out
  layernorm_kernel<<<B, 256, 0, stream>>>(ref, gamma, beta, (float*)d_out, D, 1e-5f);
}